// Round 1
// baseline (1065.655 us; speedup 1.0000x reference)
//
#include <hip/hip_runtime.h>

// BN scale constant: 1/sqrt(1+1e-5)
#define RSQ_BN 0.9999950000374997f

__device__ __forceinline__ float leaky02(float x) { return x > 0.f ? x : 0.2f * x; }

// ---------------- CSR build ----------------

__global__ void zero_i32_k(int* __restrict__ p, int n) {
    int i = blockIdx.x * 256 + threadIdx.x;
    if (i < n) p[i] = 0;
}

__global__ void hist_k(const int* __restrict__ edst, int* __restrict__ cnt, int E, int EN) {
    int i = blockIdx.x * 256 + threadIdx.x;
    if (i >= EN) return;
    int d = (i < E) ? edst[i] : (i - E);   // self-loop for i>=E
    atomicAdd(&cnt[d], 1);
}

__global__ __launch_bounds__(1024)
void scan_k(int* __restrict__ cnt_cursor,  // in: counts, out: cursor (=rowptr copy)
            int* __restrict__ rowptr, float* __restrict__ dis, int n) {
    __shared__ int sums[1024];
    int t = threadIdx.x;
    int CH = (n + 1023) >> 10;
    int b = t * CH;
    int e = min(b + CH, n);
    int s = 0;
    for (int i = b; i < e; ++i) s += cnt_cursor[i];
    sums[t] = s;
    __syncthreads();
    for (int off = 1; off < 1024; off <<= 1) {
        int v = 0;
        if (t >= off) v = sums[t - off];
        __syncthreads();
        if (t >= off) sums[t] += v;
        __syncthreads();
    }
    int run = (t == 0) ? 0 : sums[t - 1];
    for (int i = b; i < e; ++i) {
        int c = cnt_cursor[i];
        rowptr[i] = run;
        cnt_cursor[i] = run;          // cursor for scatter
        dis[i] = rsqrtf((float)c);    // deg >= 1 always (self-loop)
        run += c;
    }
    if (t == 1023) rowptr[n] = run;
}

__global__ void scatter_k(const int* __restrict__ esrc, const int* __restrict__ edst,
                          int* __restrict__ cursor, int* __restrict__ colidx, int E, int EN) {
    int i = blockIdx.x * 256 + threadIdx.x;
    if (i >= EN) return;
    int s, d;
    if (i < E) { s = esrc[i]; d = edst[i]; }
    else       { s = i - E; d = s; }
    int pos = atomicAdd(&cursor[d], 1);
    colidx[pos] = s;
}

// ---------------- dense linear: Y = act(X@W + b) [optionally *bn after act] ----------------
// X:[n,K], W:[K,M] row-major, Y:[n,M]. bng non-null => y = act(y)*(bng*RSQ_BN)+bnb (act first).

template <int K, int M>
__global__ __launch_bounds__(256)
void linear_k(const float* __restrict__ X, const float* __restrict__ W,
              const float* __restrict__ bias, const float* __restrict__ bng,
              const float* __restrict__ bnb, float* __restrict__ Y, int n, int do_relu) {
    constexpr int CG = M / 4;       // col groups of 4
    constexpr int RPI = 256 / CG;   // rows per block-iteration
    __shared__ float Ws[K * M];
    for (int i = threadIdx.x; i < K * M; i += 256) Ws[i] = W[i];
    __syncthreads();
    const int cg = threadIdx.x % CG;
    const int r = threadIdx.x / CG;
    const int c = cg * 4;
    for (int row0 = blockIdx.x * RPI; row0 < n; row0 += gridDim.x * RPI) {
        int row = row0 + r;
        if (row >= n) continue;
        const float* xr = X + (size_t)row * K;
        float ax = 0.f, ay = 0.f, az = 0.f, aw = 0.f;
#pragma unroll 4
        for (int k = 0; k < K; k += 4) {
            float4 xv = *reinterpret_cast<const float4*>(xr + k);
            const float* wp = Ws + k * M + c;
            float4 w0 = *reinterpret_cast<const float4*>(wp);
            float4 w1 = *reinterpret_cast<const float4*>(wp + M);
            float4 w2 = *reinterpret_cast<const float4*>(wp + 2 * M);
            float4 w3 = *reinterpret_cast<const float4*>(wp + 3 * M);
            ax += xv.x * w0.x + xv.y * w1.x + xv.z * w2.x + xv.w * w3.x;
            ay += xv.x * w0.y + xv.y * w1.y + xv.z * w2.y + xv.w * w3.y;
            az += xv.x * w0.z + xv.y * w1.z + xv.z * w2.z + xv.w * w3.z;
            aw += xv.x * w0.w + xv.y * w1.w + xv.z * w2.w + xv.w * w3.w;
        }
        if (bias) { ax += bias[c]; ay += bias[c + 1]; az += bias[c + 2]; aw += bias[c + 3]; }
        if (do_relu) {
            ax = fmaxf(ax, 0.f); ay = fmaxf(ay, 0.f); az = fmaxf(az, 0.f); aw = fmaxf(aw, 0.f);
        }
        if (bng) {
            ax = ax * (bng[c] * RSQ_BN) + bnb[c];
            ay = ay * (bng[c + 1] * RSQ_BN) + bnb[c + 1];
            az = az * (bng[c + 2] * RSQ_BN) + bnb[c + 2];
            aw = aw * (bng[c + 3] * RSQ_BN) + bnb[c + 3];
        }
        *reinterpret_cast<float4*>(Y + (size_t)row * M + c) = make_float4(ax, ay, az, aw);
    }
}

// ---------------- GCN aggregation (gather over CSR) + fused epilogue ----------------
// Y[i] = relu(bn(sum_j dis[s_j]*T[s_j] * dis[i] + bias)) [+ res]

__global__ __launch_bounds__(256)
void gcn_gather_k(const int* __restrict__ rowptr, const int* __restrict__ colidx,
                  const float* __restrict__ dis, const float* __restrict__ T,
                  const float* __restrict__ bias, const float* __restrict__ bng,
                  const float* __restrict__ bnb, const float* __restrict__ res,
                  float* __restrict__ Y, int n) {
    int idx = blockIdx.x * 256 + threadIdx.x;
    int i = idx >> 5;
    if (i >= n) return;
    int c = (idx & 31) << 2;
    int p0 = rowptr[i], p1 = rowptr[i + 1];
    float ax = 0.f, ay = 0.f, az = 0.f, aw = 0.f;
    for (int p = p0; p < p1; ++p) {
        int s = colidx[p];
        float w = dis[s];
        float4 v = *reinterpret_cast<const float4*>(T + (size_t)s * 128 + c);
        ax += v.x * w; ay += v.y * w; az += v.z * w; aw += v.w * w;
    }
    float di = dis[i];
    ax = ax * di + bias[c];
    ay = ay * di + bias[c + 1];
    az = az * di + bias[c + 2];
    aw = aw * di + bias[c + 3];
    ax = fmaxf(ax * (bng[c] * RSQ_BN) + bnb[c], 0.f);
    ay = fmaxf(ay * (bng[c + 1] * RSQ_BN) + bnb[c + 1], 0.f);
    az = fmaxf(az * (bng[c + 2] * RSQ_BN) + bnb[c + 2], 0.f);
    aw = fmaxf(aw * (bng[c + 3] * RSQ_BN) + bnb[c + 3], 0.f);
    if (res) {
        float4 rv = *reinterpret_cast<const float4*>(res + (size_t)i * 128 + c);
        ax += rv.x; ay += rv.y; az += rv.z; aw += rv.w;
    }
    *reinterpret_cast<float4*>(Y + (size_t)i * 128 + c) = make_float4(ax, ay, az, aw);
}

// ---------------- GAT ----------------

// per (node, head): asrc/adst dot products
__global__ void gat_dots_k(const float* __restrict__ XH, const float* __restrict__ Asrc,
                           const float* __restrict__ Adst, float* __restrict__ av,
                           float* __restrict__ bv, int n, int hh) {
    int idx = blockIdx.x * 256 + threadIdx.x;
    if (idx >= n * hh) return;
    int i = idx / hh;
    int h = idx - i * hh;
    int C = 128 / hh;
    const float* xr = XH + (size_t)i * 128 + h * C;
    const float* ap = Asrc + h * C;
    const float* bp = Adst + h * C;
    float sa = 0.f, sd = 0.f;
    for (int cc = 0; cc < C; ++cc) {
        float v = xr[cc];
        sa += v * ap[cc];
        sd += v * bp[cc];
    }
    av[idx] = sa;
    bv[idx] = sd;
}

// per (node, head): segment max + sum(exp) over CSR row  -> mden, sinv
__global__ void gat_k1(const int* __restrict__ rowptr, const int* __restrict__ colidx,
                       const float* __restrict__ av, const float* __restrict__ bv,
                       float* __restrict__ mden, float* __restrict__ sinv, int n, int hh) {
    int idx = blockIdx.x * 256 + threadIdx.x;
    if (idx >= n * hh) return;
    int i = idx / hh;
    int h = idx - i * hh;
    float ad = bv[idx];
    int p0 = rowptr[i], p1 = rowptr[i + 1];
    float m = -3.0e38f;
    for (int p = p0; p < p1; ++p) {
        float e = leaky02(av[colidx[p] * hh + h] + ad);
        m = fmaxf(m, e);
    }
    float s = 0.f;
    for (int p = p0; p < p1; ++p) {
        float e = leaky02(av[colidx[p] * hh + h] + ad);
        s += expf(e - m);
    }
    mden[idx] = m;
    sinv[idx] = 1.f / (s + 1e-16f);
}

// per (node, 4 cols): aggregate alpha-weighted xh + fused (bias, bn, elu, feat_imp)
__global__ __launch_bounds__(256)
void gat_k2(const int* __restrict__ rowptr, const int* __restrict__ colidx,
            const float* __restrict__ XH, const float* __restrict__ av,
            const float* __restrict__ bv, const float* __restrict__ mden,
            const float* __restrict__ sinv, const float* __restrict__ bias,
            const float* __restrict__ bng, const float* __restrict__ bnb,
            const float* __restrict__ fimp, float* __restrict__ Y, int n, int hh, int log2C) {
    int idx = blockIdx.x * 256 + threadIdx.x;
    int i = idx >> 5;
    if (i >= n) return;
    int c = (idx & 31) << 2;
    int h = c >> log2C;
    float ad = bv[i * hh + h];
    float m = mden[i * hh + h];
    float si = sinv[i * hh + h];
    int p0 = rowptr[i], p1 = rowptr[i + 1];
    float ax = 0.f, ay = 0.f, az = 0.f, aw = 0.f;
    for (int p = p0; p < p1; ++p) {
        int s = colidx[p];
        float e = leaky02(av[s * hh + h] + ad);
        float a = expf(e - m) * si;
        float4 v = *reinterpret_cast<const float4*>(XH + (size_t)s * 128 + c);
        ax += v.x * a; ay += v.y * a; az += v.z * a; aw += v.w * a;
    }
    ax += bias[c]; ay += bias[c + 1]; az += bias[c + 2]; aw += bias[c + 3];
    ax = ax * (bng[c] * RSQ_BN) + bnb[c];
    ay = ay * (bng[c + 1] * RSQ_BN) + bnb[c + 1];
    az = az * (bng[c + 2] * RSQ_BN) + bnb[c + 2];
    aw = aw * (bng[c + 3] * RSQ_BN) + bnb[c + 3];
    ax = ax > 0.f ? ax : expm1f(ax);
    ay = ay > 0.f ? ay : expm1f(ay);
    az = az > 0.f ? az : expm1f(az);
    aw = aw > 0.f ? aw : expm1f(aw);
    if (fimp) { ax *= fimp[c]; ay *= fimp[c + 1]; az *= fimp[c + 2]; aw *= fimp[c + 3]; }
    *reinterpret_cast<float4*>(Y + (size_t)i * 128 + c) = make_float4(ax, ay, az, aw);
}

// ---------------- fusion tail ----------------

__global__ void blend_k(const float* __restrict__ G, const float* __restrict__ R,
                        float* __restrict__ F, int n4) {
    int idx = blockIdx.x * 256 + threadIdx.x;
    if (idx >= n4) return;
    float4 g = reinterpret_cast<const float4*>(G)[idx];
    float4 r = reinterpret_cast<const float4*>(R)[idx];
    reinterpret_cast<float4*>(F)[idx] =
        make_float4(0.6f * g.x + 0.4f * r.x, 0.6f * g.y + 0.4f * r.y,
                    0.6f * g.z + 0.4f * r.z, 0.6f * g.w + 0.4f * r.w);
}

__global__ void fin2_k(const float* __restrict__ H, const float* __restrict__ W,
                       const float* __restrict__ b, float* __restrict__ out, int n) {
    int i = blockIdx.x * 256 + threadIdx.x;
    if (i >= n) return;
    const float* hr = H + (size_t)i * 64;
    float o0 = b[0], o1 = b[1];
#pragma unroll
    for (int k = 0; k < 64; ++k) {
        float v = hr[k];
        o0 += v * W[2 * k];
        o1 += v * W[2 * k + 1];
    }
    out[2 * i] = o0;
    out[2 * i + 1] = o1;
}

// ---------------- host orchestration ----------------

static inline int cdiv(int a, int b) { return (a + b - 1) / b; }

extern "C" void kernel_launch(void* const* d_in, const int* in_sizes, int n_in,
                              void* d_out, int out_size, void* d_ws, size_t ws_size,
                              hipStream_t stream) {
    const float* x       = (const float*)d_in[0];
    const int*   ei      = (const int*)d_in[1];
    const float* gcn_in_w = (const float*)d_in[2];
    const float* gcn_in_b = (const float*)d_in[3];
    const float* gcn_res_w = (const float*)d_in[4];
    const float* gcn_res_b = (const float*)d_in[5];
    const float* gcn_w   = (const float*)d_in[6];
    const float* gcn_b   = (const float*)d_in[7];
    const float* gcn_bn_g = (const float*)d_in[8];
    const float* gcn_bn_b = (const float*)d_in[9];
    const float* gcn_c1w = (const float*)d_in[10];
    const float* gcn_c1b = (const float*)d_in[11];
    const float* gcn_c2w = (const float*)d_in[12];
    const float* gcn_c2b = (const float*)d_in[13];
    const float* gcn_c3w = (const float*)d_in[14];
    const float* gcn_c3b = (const float*)d_in[15];
    const float* gat_in_w = (const float*)d_in[16];
    const float* gat_in_b = (const float*)d_in[17];
    const float* gat_w   = (const float*)d_in[18];
    const float* gat_asrc = (const float*)d_in[19];
    const float* gat_adst = (const float*)d_in[20];
    const float* gat_b   = (const float*)d_in[21];
    const float* gat_bn_g = (const float*)d_in[22];
    const float* gat_bn_b = (const float*)d_in[23];
    const float* feat_imp = (const float*)d_in[24];
    const float* gat_c1w = (const float*)d_in[25];
    const float* gat_c1b = (const float*)d_in[26];
    const float* gat_cbn_g = (const float*)d_in[27];
    const float* gat_cbn_b = (const float*)d_in[28];
    const float* gat_c2w = (const float*)d_in[29];
    const float* gat_c2b = (const float*)d_in[30];
    const float* gat_c3w = (const float*)d_in[31];
    const float* gat_c3b = (const float*)d_in[32];
    const float* fin_w   = (const float*)d_in[33];
    const float* fin_b   = (const float*)d_in[34];
    const float* fin_bn_g = (const float*)d_in[35];
    const float* fin_bn_b = (const float*)d_in[36];
    const float* fin2_w  = (const float*)d_in[37];
    const float* fin2_b  = (const float*)d_in[38];

    const int N = in_sizes[0] / 64;
    const int E = in_sizes[1] / 2;
    const int EN = E + N;
    const int* esrc = ei;
    const int* edst = ei + E;

    // workspace carve (256B aligned)
    char* wp = (char*)d_ws;
    auto alloc = [&](size_t bytes) -> void* {
        void* p = (void*)wp;
        wp += (bytes + 255) & ~(size_t)255;
        return p;
    };
    int* rowptr = (int*)alloc((size_t)(N + 1) * 4);
    int* cursor = (int*)alloc((size_t)N * 4);
    int* colidx = (int*)alloc((size_t)EN * 4);
    float* dis  = (float*)alloc((size_t)N * 4);
    float* A    = (float*)alloc((size_t)N * 128 * 4);
    float* B    = (float*)alloc((size_t)N * 128 * 4);
    float* R    = (float*)alloc((size_t)N * 128 * 4);
    float* T    = (float*)alloc((size_t)N * 128 * 4);
    float* GOUT = (float*)alloc((size_t)N * 128 * 4);
    float* h1   = (float*)alloc((size_t)N * 64 * 4);
    float* h2   = (float*)alloc((size_t)N * 32 * 4);
    float* avv  = (float*)alloc((size_t)N * 4 * 4);
    float* bvv  = (float*)alloc((size_t)N * 4 * 4);
    float* mden = (float*)alloc((size_t)N * 4 * 4);
    float* sinv = (float*)alloc((size_t)N * 4 * 4);

    // ---- CSR build (dst-grouped, self-loops appended) ----
    zero_i32_k<<<cdiv(N, 256), 256, 0, stream>>>(cursor, N);
    hist_k<<<cdiv(EN, 256), 256, 0, stream>>>(edst, cursor, E, EN);
    scan_k<<<1, 1024, 0, stream>>>(cursor, rowptr, dis, N);
    scatter_k<<<cdiv(EN, 256), 256, 0, stream>>>(esrc, edst, cursor, colidx, E, EN);

    const int gN32 = cdiv(N * 32, 256);

    // ---- GCN branch ----
    linear_k<64, 128><<<cdiv(N, 8), 256, 0, stream>>>(x, gcn_in_w, gcn_in_b, nullptr, nullptr, A, N, 0);
    linear_k<64, 128><<<cdiv(N, 8), 256, 0, stream>>>(x, gcn_res_w, gcn_res_b, nullptr, nullptr, R, N, 0);
    float* cur = A;
    float* nxt = B;
    for (int i = 0; i < 3; ++i) {
        linear_k<128, 128><<<cdiv(N, 8), 256, 0, stream>>>(cur, gcn_w + (size_t)i * 16384,
                                                           nullptr, nullptr, nullptr, T, N, 0);
        gcn_gather_k<<<gN32, 256, 0, stream>>>(rowptr, colidx, dis, T, gcn_b + i * 128,
                                               gcn_bn_g + i * 128, gcn_bn_b + i * 128,
                                               (i == 1) ? R : nullptr, nxt, N);
        float* t = cur; cur = nxt; nxt = t;
    }
    // cur == final xp (in B)
    linear_k<128, 64><<<cdiv(N, 16), 256, 0, stream>>>(cur, gcn_c1w, gcn_c1b, nullptr, nullptr, h1, N, 1);
    linear_k<64, 32><<<cdiv(N, 32), 256, 0, stream>>>(h1, gcn_c2w, gcn_c2b, nullptr, nullptr, h2, N, 1);
    linear_k<32, 128><<<cdiv(N, 8), 256, 0, stream>>>(h2, gcn_c3w, gcn_c3b, nullptr, nullptr, GOUT, N, 0);

    // ---- GAT branch ----
    float* xg = A;
    float* xgn = B;
    linear_k<64, 128><<<cdiv(N, 8), 256, 0, stream>>>(x, gat_in_w, gat_in_b, nullptr, nullptr, xg, N, 0);
    const int heads_arr[3] = {4, 4, 1};
    for (int i = 0; i < 3; ++i) {
        int hh = heads_arr[i];
        int log2C = (hh == 4) ? 5 : 7;
        linear_k<128, 128><<<cdiv(N, 8), 256, 0, stream>>>(xg, gat_w + (size_t)i * 16384,
                                                           nullptr, nullptr, nullptr, T, N, 0);
        gat_dots_k<<<cdiv(N * hh, 256), 256, 0, stream>>>(T, gat_asrc + i * 128, gat_adst + i * 128,
                                                          avv, bvv, N, hh);
        gat_k1<<<cdiv(N * hh, 256), 256, 0, stream>>>(rowptr, colidx, avv, bvv, mden, sinv, N, hh);
        gat_k2<<<gN32, 256, 0, stream>>>(rowptr, colidx, T, avv, bvv, mden, sinv,
                                         gat_b + i * 128, gat_bn_g + i * 128, gat_bn_b + i * 128,
                                         (i == 2) ? feat_imp : nullptr, xgn, N, hh, log2C);
        float* t = xg; xg = xgn; xgn = t;
    }
    // xg == final GAT features (feat_imp already applied), in B
    linear_k<128, 64><<<cdiv(N, 16), 256, 0, stream>>>(xg, gat_c1w, gat_c1b, gat_cbn_g, gat_cbn_b, h1, N, 1);
    linear_k<64, 32><<<cdiv(N, 32), 256, 0, stream>>>(h1, gat_c2w, gat_c2b, nullptr, nullptr, h2, N, 1);
    linear_k<32, 128><<<cdiv(N, 8), 256, 0, stream>>>(h2, gat_c3w, gat_c3b, nullptr, nullptr, R, N, 0);

    // ---- fusion tail ----
    blend_k<<<gN32, 256, 0, stream>>>(GOUT, R, T, N * 32);
    linear_k<128, 64><<<cdiv(N, 16), 256, 0, stream>>>(T, fin_w, fin_b, fin_bn_g, fin_bn_b, h1, N, 1);
    fin2_k<<<cdiv(N, 256), 256, 0, stream>>>(h1, fin2_w, fin2_b, (float*)d_out, N);
}

// Round 2
// 960.460 us; speedup vs baseline: 1.1095x; 1.1095x over previous
//
#include <hip/hip_runtime.h>

// BN scale constant: 1/sqrt(1+1e-5)
#define RSQ_BN 0.9999950000374997f

__device__ __forceinline__ float leaky02(float x) { return x > 0.f ? x : 0.2f * x; }

// ---------------- CSR build ----------------

__global__ void zero_i32_k(int* __restrict__ p, int n) {
    int i = blockIdx.x * 256 + threadIdx.x;
    if (i < n) p[i] = 0;
}

__global__ void hist_k(const int* __restrict__ edst, int* __restrict__ cnt, int E, int EN) {
    int i = blockIdx.x * 256 + threadIdx.x;
    if (i >= EN) return;
    int d = (i < E) ? edst[i] : (i - E);   // self-loop for i>=E
    atomicAdd(&cnt[d], 1);
}

// Phase A: per-block exclusive scan of cnt -> rowptr(local), block total -> bsum
__global__ __launch_bounds__(256)
void scanA_k(const int* __restrict__ cnt, int* __restrict__ rowptr,
             int* __restrict__ bsum, int n) {
    __shared__ int sh[256];
    int t = threadIdx.x;
    int i = blockIdx.x * 256 + t;
    int v = (i < n) ? cnt[i] : 0;
    sh[t] = v;
    __syncthreads();
#pragma unroll
    for (int off = 1; off < 256; off <<= 1) {
        int u = 0;
        if (t >= off) u = sh[t - off];
        __syncthreads();
        sh[t] += u;
        __syncthreads();
    }
    if (i < n) rowptr[i] = sh[t] - v;          // exclusive
    if (t == 255) bsum[blockIdx.x] = sh[255];  // block total
}

// Phase B: single-block exclusive scan of bsum (nb <= 256)
__global__ __launch_bounds__(256)
void scanB_k(int* __restrict__ bsum, int nb) {
    __shared__ int sh[256];
    int t = threadIdx.x;
    int v = (t < nb) ? bsum[t] : 0;
    sh[t] = v;
    __syncthreads();
#pragma unroll
    for (int off = 1; off < 256; off <<= 1) {
        int u = 0;
        if (t >= off) u = sh[t - off];
        __syncthreads();
        sh[t] += u;
        __syncthreads();
    }
    if (t < nb) bsum[t] = sh[t] - v;
}

// Phase C: add block offsets, emit cursor + dis; rowptr[n] = EN (known total)
__global__ __launch_bounds__(256)
void scanC_k(const int* __restrict__ cnt, const int* __restrict__ bsum,
             int* __restrict__ rowptr, int* __restrict__ cursor,
             float* __restrict__ dis, int n, int EN) {
    int i = blockIdx.x * 256 + threadIdx.x;
    if (i < n) {
        int r = rowptr[i] + bsum[blockIdx.x];
        rowptr[i] = r;
        cursor[i] = r;
        dis[i] = rsqrtf((float)cnt[i]);   // deg >= 1 always (self-loop)
    }
    if (i == 0) rowptr[n] = EN;
}

__global__ void scatter_k(const int* __restrict__ esrc, const int* __restrict__ edst,
                          int* __restrict__ cursor, int* __restrict__ colidx, int E, int EN) {
    int i = blockIdx.x * 256 + threadIdx.x;
    if (i >= EN) return;
    int s, d;
    if (i < E) { s = esrc[i]; d = edst[i]; }
    else       { s = i - E; d = s; }
    int pos = atomicAdd(&cursor[d], 1);
    colidx[pos] = s;
}

// ---------------- dense linear: Y = act(X@W + b) [optionally *bn after act] ----------------
// X:[n,K], W:[K,M] row-major, Y:[n,M]. bng non-null => y = act(y)*(bng*RSQ_BN)+bnb (act first).

template <int K, int M>
__global__ __launch_bounds__(256)
void linear_k(const float* __restrict__ X, const float* __restrict__ W,
              const float* __restrict__ bias, const float* __restrict__ bng,
              const float* __restrict__ bnb, float* __restrict__ Y, int n, int do_relu) {
    constexpr int CG = M / 4;       // col groups of 4
    constexpr int RPI = 256 / CG;   // rows per block-iteration
    __shared__ float Ws[K * M];
    for (int i = threadIdx.x; i < K * M; i += 256) Ws[i] = W[i];
    __syncthreads();
    const int cg = threadIdx.x % CG;
    const int r = threadIdx.x / CG;
    const int c = cg * 4;
    for (int row0 = blockIdx.x * RPI; row0 < n; row0 += gridDim.x * RPI) {
        int row = row0 + r;
        if (row >= n) continue;
        const float* xr = X + (size_t)row * K;
        float ax = 0.f, ay = 0.f, az = 0.f, aw = 0.f;
#pragma unroll 4
        for (int k = 0; k < K; k += 4) {
            float4 xv = *reinterpret_cast<const float4*>(xr + k);
            const float* wp = Ws + k * M + c;
            float4 w0 = *reinterpret_cast<const float4*>(wp);
            float4 w1 = *reinterpret_cast<const float4*>(wp + M);
            float4 w2 = *reinterpret_cast<const float4*>(wp + 2 * M);
            float4 w3 = *reinterpret_cast<const float4*>(wp + 3 * M);
            ax += xv.x * w0.x + xv.y * w1.x + xv.z * w2.x + xv.w * w3.x;
            ay += xv.x * w0.y + xv.y * w1.y + xv.z * w2.y + xv.w * w3.y;
            az += xv.x * w0.z + xv.y * w1.z + xv.z * w2.z + xv.w * w3.z;
            aw += xv.x * w0.w + xv.y * w1.w + xv.z * w2.w + xv.w * w3.w;
        }
        if (bias) { ax += bias[c]; ay += bias[c + 1]; az += bias[c + 2]; aw += bias[c + 3]; }
        if (do_relu) {
            ax = fmaxf(ax, 0.f); ay = fmaxf(ay, 0.f); az = fmaxf(az, 0.f); aw = fmaxf(aw, 0.f);
        }
        if (bng) {
            ax = ax * (bng[c] * RSQ_BN) + bnb[c];
            ay = ay * (bng[c + 1] * RSQ_BN) + bnb[c + 1];
            az = az * (bng[c + 2] * RSQ_BN) + bnb[c + 2];
            aw = aw * (bng[c + 3] * RSQ_BN) + bnb[c + 3];
        }
        *reinterpret_cast<float4*>(Y + (size_t)row * M + c) = make_float4(ax, ay, az, aw);
    }
}

// ---------------- GCN aggregation (gather over CSR) + fused epilogue ----------------

__global__ __launch_bounds__(256)
void gcn_gather_k(const int* __restrict__ rowptr, const int* __restrict__ colidx,
                  const float* __restrict__ dis, const float* __restrict__ T,
                  const float* __restrict__ bias, const float* __restrict__ bng,
                  const float* __restrict__ bnb, const float* __restrict__ res,
                  float* __restrict__ Y, int n) {
    int idx = blockIdx.x * 256 + threadIdx.x;
    int i = idx >> 5;
    if (i >= n) return;
    int c = (idx & 31) << 2;
    int p0 = rowptr[i], p1 = rowptr[i + 1];
    float ax = 0.f, ay = 0.f, az = 0.f, aw = 0.f;
    for (int p = p0; p < p1; ++p) {
        int s = colidx[p];
        float w = dis[s];
        float4 v = *reinterpret_cast<const float4*>(T + (size_t)s * 128 + c);
        ax += v.x * w; ay += v.y * w; az += v.z * w; aw += v.w * w;
    }
    float di = dis[i];
    ax = ax * di + bias[c];
    ay = ay * di + bias[c + 1];
    az = az * di + bias[c + 2];
    aw = aw * di + bias[c + 3];
    ax = fmaxf(ax * (bng[c] * RSQ_BN) + bnb[c], 0.f);
    ay = fmaxf(ay * (bng[c + 1] * RSQ_BN) + bnb[c + 1], 0.f);
    az = fmaxf(az * (bng[c + 2] * RSQ_BN) + bnb[c + 2], 0.f);
    aw = fmaxf(aw * (bng[c + 3] * RSQ_BN) + bnb[c + 3], 0.f);
    if (res) {
        float4 rv = *reinterpret_cast<const float4*>(res + (size_t)i * 128 + c);
        ax += rv.x; ay += rv.y; az += rv.z; aw += rv.w;
    }
    *reinterpret_cast<float4*>(Y + (size_t)i * 128 + c) = make_float4(ax, ay, az, aw);
}

// ---------------- GAT ----------------

__global__ void gat_dots_k(const float* __restrict__ XH, const float* __restrict__ Asrc,
                           const float* __restrict__ Adst, float* __restrict__ av,
                           float* __restrict__ bv, int n, int hh) {
    int idx = blockIdx.x * 256 + threadIdx.x;
    if (idx >= n * hh) return;
    int i = idx / hh;
    int h = idx - i * hh;
    int C = 128 / hh;
    const float* xr = XH + (size_t)i * 128 + h * C;
    const float* ap = Asrc + h * C;
    const float* bp = Adst + h * C;
    float sa = 0.f, sd = 0.f;
    for (int cc = 0; cc < C; cc += 4) {
        float4 v = *reinterpret_cast<const float4*>(xr + cc);
        float4 a = *reinterpret_cast<const float4*>(ap + cc);
        float4 b = *reinterpret_cast<const float4*>(bp + cc);
        sa += v.x * a.x + v.y * a.y + v.z * a.z + v.w * a.w;
        sd += v.x * b.x + v.y * b.y + v.z * b.z + v.w * b.w;
    }
    av[idx] = sa;
    bv[idx] = sd;
}

__global__ void gat_k1(const int* __restrict__ rowptr, const int* __restrict__ colidx,
                       const float* __restrict__ av, const float* __restrict__ bv,
                       float* __restrict__ mden, float* __restrict__ sinv, int n, int hh) {
    int idx = blockIdx.x * 256 + threadIdx.x;
    if (idx >= n * hh) return;
    int i = idx / hh;
    int h = idx - i * hh;
    float ad = bv[idx];
    int p0 = rowptr[i], p1 = rowptr[i + 1];
    float m = -3.0e38f;
    for (int p = p0; p < p1; ++p) {
        float e = leaky02(av[colidx[p] * hh + h] + ad);
        m = fmaxf(m, e);
    }
    float s = 0.f;
    for (int p = p0; p < p1; ++p) {
        float e = leaky02(av[colidx[p] * hh + h] + ad);
        s += expf(e - m);
    }
    mden[idx] = m;
    sinv[idx] = 1.f / (s + 1e-16f);
}

__global__ __launch_bounds__(256)
void gat_k2(const int* __restrict__ rowptr, const int* __restrict__ colidx,
            const float* __restrict__ XH, const float* __restrict__ av,
            const float* __restrict__ bv, const float* __restrict__ mden,
            const float* __restrict__ sinv, const float* __restrict__ bias,
            const float* __restrict__ bng, const float* __restrict__ bnb,
            const float* __restrict__ fimp, float* __restrict__ Y, int n, int hh, int log2C) {
    int idx = blockIdx.x * 256 + threadIdx.x;
    int i = idx >> 5;
    if (i >= n) return;
    int c = (idx & 31) << 2;
    int h = c >> log2C;
    float ad = bv[i * hh + h];
    float m = mden[i * hh + h];
    float si = sinv[i * hh + h];
    int p0 = rowptr[i], p1 = rowptr[i + 1];
    float ax = 0.f, ay = 0.f, az = 0.f, aw = 0.f;
    for (int p = p0; p < p1; ++p) {
        int s = colidx[p];
        float e = leaky02(av[s * hh + h] + ad);
        float a = expf(e - m) * si;
        float4 v = *reinterpret_cast<const float4*>(XH + (size_t)s * 128 + c);
        ax += v.x * a; ay += v.y * a; az += v.z * a; aw += v.w * a;
    }
    ax += bias[c]; ay += bias[c + 1]; az += bias[c + 2]; aw += bias[c + 3];
    ax = ax * (bng[c] * RSQ_BN) + bnb[c];
    ay = ay * (bng[c + 1] * RSQ_BN) + bnb[c + 1];
    az = az * (bng[c + 2] * RSQ_BN) + bnb[c + 2];
    aw = aw * (bng[c + 3] * RSQ_BN) + bnb[c + 3];
    ax = ax > 0.f ? ax : expm1f(ax);
    ay = ay > 0.f ? ay : expm1f(ay);
    az = az > 0.f ? az : expm1f(az);
    aw = aw > 0.f ? aw : expm1f(aw);
    if (fimp) { ax *= fimp[c]; ay *= fimp[c + 1]; az *= fimp[c + 2]; aw *= fimp[c + 3]; }
    *reinterpret_cast<float4*>(Y + (size_t)i * 128 + c) = make_float4(ax, ay, az, aw);
}

// ---------------- fusion tail ----------------

__global__ void blend_k(const float* __restrict__ G, const float* __restrict__ R,
                        float* __restrict__ F, int n4) {
    int idx = blockIdx.x * 256 + threadIdx.x;
    if (idx >= n4) return;
    float4 g = reinterpret_cast<const float4*>(G)[idx];
    float4 r = reinterpret_cast<const float4*>(R)[idx];
    reinterpret_cast<float4*>(F)[idx] =
        make_float4(0.6f * g.x + 0.4f * r.x, 0.6f * g.y + 0.4f * r.y,
                    0.6f * g.z + 0.4f * r.z, 0.6f * g.w + 0.4f * r.w);
}

__global__ void fin2_k(const float* __restrict__ H, const float* __restrict__ W,
                       const float* __restrict__ b, float* __restrict__ out, int n) {
    int i = blockIdx.x * 256 + threadIdx.x;
    if (i >= n) return;
    const float* hr = H + (size_t)i * 64;
    float o0 = b[0], o1 = b[1];
#pragma unroll
    for (int k = 0; k < 64; ++k) {
        float v = hr[k];
        o0 += v * W[2 * k];
        o1 += v * W[2 * k + 1];
    }
    out[2 * i] = o0;
    out[2 * i + 1] = o1;
}

// ---------------- host orchestration ----------------

static inline int cdiv(int a, int b) { return (a + b - 1) / b; }

extern "C" void kernel_launch(void* const* d_in, const int* in_sizes, int n_in,
                              void* d_out, int out_size, void* d_ws, size_t ws_size,
                              hipStream_t stream) {
    const float* x       = (const float*)d_in[0];
    const int*   ei      = (const int*)d_in[1];
    const float* gcn_in_w = (const float*)d_in[2];
    const float* gcn_in_b = (const float*)d_in[3];
    const float* gcn_res_w = (const float*)d_in[4];
    const float* gcn_res_b = (const float*)d_in[5];
    const float* gcn_w   = (const float*)d_in[6];
    const float* gcn_b   = (const float*)d_in[7];
    const float* gcn_bn_g = (const float*)d_in[8];
    const float* gcn_bn_b = (const float*)d_in[9];
    const float* gcn_c1w = (const float*)d_in[10];
    const float* gcn_c1b = (const float*)d_in[11];
    const float* gcn_c2w = (const float*)d_in[12];
    const float* gcn_c2b = (const float*)d_in[13];
    const float* gcn_c3w = (const float*)d_in[14];
    const float* gcn_c3b = (const float*)d_in[15];
    const float* gat_in_w = (const float*)d_in[16];
    const float* gat_in_b = (const float*)d_in[17];
    const float* gat_w   = (const float*)d_in[18];
    const float* gat_asrc = (const float*)d_in[19];
    const float* gat_adst = (const float*)d_in[20];
    const float* gat_b   = (const float*)d_in[21];
    const float* gat_bn_g = (const float*)d_in[22];
    const float* gat_bn_b = (const float*)d_in[23];
    const float* feat_imp = (const float*)d_in[24];
    const float* gat_c1w = (const float*)d_in[25];
    const float* gat_c1b = (const float*)d_in[26];
    const float* gat_cbn_g = (const float*)d_in[27];
    const float* gat_cbn_b = (const float*)d_in[28];
    const float* gat_c2w = (const float*)d_in[29];
    const float* gat_c2b = (const float*)d_in[30];
    const float* gat_c3w = (const float*)d_in[31];
    const float* gat_c3b = (const float*)d_in[32];
    const float* fin_w   = (const float*)d_in[33];
    const float* fin_b   = (const float*)d_in[34];
    const float* fin_bn_g = (const float*)d_in[35];
    const float* fin_bn_b = (const float*)d_in[36];
    const float* fin2_w  = (const float*)d_in[37];
    const float* fin2_b  = (const float*)d_in[38];

    const int N = in_sizes[0] / 64;
    const int E = in_sizes[1] / 2;
    const int EN = E + N;
    const int* esrc = ei;
    const int* edst = ei + E;

    // workspace carve (256B aligned)
    char* wp = (char*)d_ws;
    auto alloc = [&](size_t bytes) -> void* {
        void* p = (void*)wp;
        wp += (bytes + 255) & ~(size_t)255;
        return p;
    };
    int* cnt    = (int*)alloc((size_t)N * 4);
    int* rowptr = (int*)alloc((size_t)(N + 1) * 4);
    int* cursor = (int*)alloc((size_t)N * 4);
    int* bsum   = (int*)alloc((size_t)256 * 4);
    int* colidx = (int*)alloc((size_t)EN * 4);
    float* dis  = (float*)alloc((size_t)N * 4);
    float* A    = (float*)alloc((size_t)N * 128 * 4);
    float* B    = (float*)alloc((size_t)N * 128 * 4);
    float* R    = (float*)alloc((size_t)N * 128 * 4);
    float* T    = (float*)alloc((size_t)N * 128 * 4);
    float* GOUT = (float*)alloc((size_t)N * 128 * 4);
    float* h1   = (float*)alloc((size_t)N * 64 * 4);
    float* h2   = (float*)alloc((size_t)N * 32 * 4);
    float* avv  = (float*)alloc((size_t)N * 4 * 4);
    float* bvv  = (float*)alloc((size_t)N * 4 * 4);
    float* mden = (float*)alloc((size_t)N * 4 * 4);
    float* sinv = (float*)alloc((size_t)N * 4 * 4);

    // ---- CSR build (dst-grouped, self-loops appended) ----
    const int nScanB = cdiv(N, 256);   // 118 for N=30000; must be <= 256
    zero_i32_k<<<cdiv(N, 256), 256, 0, stream>>>(cnt, N);
    hist_k<<<cdiv(EN, 256), 256, 0, stream>>>(edst, cnt, E, EN);
    scanA_k<<<nScanB, 256, 0, stream>>>(cnt, rowptr, bsum, N);
    scanB_k<<<1, 256, 0, stream>>>(bsum, nScanB);
    scanC_k<<<nScanB, 256, 0, stream>>>(cnt, bsum, rowptr, cursor, dis, N, EN);
    scatter_k<<<cdiv(EN, 256), 256, 0, stream>>>(esrc, edst, cursor, colidx, E, EN);

    const int gN32 = cdiv(N * 32, 256);

    // ---- GCN branch ----
    linear_k<64, 128><<<cdiv(N, 8), 256, 0, stream>>>(x, gcn_in_w, gcn_in_b, nullptr, nullptr, A, N, 0);
    linear_k<64, 128><<<cdiv(N, 8), 256, 0, stream>>>(x, gcn_res_w, gcn_res_b, nullptr, nullptr, R, N, 0);
    float* cur = A;
    float* nxt = B;
    for (int i = 0; i < 3; ++i) {
        linear_k<128, 128><<<cdiv(N, 8), 256, 0, stream>>>(cur, gcn_w + (size_t)i * 16384,
                                                           nullptr, nullptr, nullptr, T, N, 0);
        gcn_gather_k<<<gN32, 256, 0, stream>>>(rowptr, colidx, dis, T, gcn_b + i * 128,
                                               gcn_bn_g + i * 128, gcn_bn_b + i * 128,
                                               (i == 1) ? R : nullptr, nxt, N);
        float* t = cur; cur = nxt; nxt = t;
    }
    linear_k<128, 64><<<cdiv(N, 16), 256, 0, stream>>>(cur, gcn_c1w, gcn_c1b, nullptr, nullptr, h1, N, 1);
    linear_k<64, 32><<<cdiv(N, 32), 256, 0, stream>>>(h1, gcn_c2w, gcn_c2b, nullptr, nullptr, h2, N, 1);
    linear_k<32, 128><<<cdiv(N, 8), 256, 0, stream>>>(h2, gcn_c3w, gcn_c3b, nullptr, nullptr, GOUT, N, 0);

    // ---- GAT branch ----
    float* xg = A;
    float* xgn = B;
    linear_k<64, 128><<<cdiv(N, 8), 256, 0, stream>>>(x, gat_in_w, gat_in_b, nullptr, nullptr, xg, N, 0);
    const int heads_arr[3] = {4, 4, 1};
    for (int i = 0; i < 3; ++i) {
        int hh = heads_arr[i];
        int log2C = (hh == 4) ? 5 : 7;
        linear_k<128, 128><<<cdiv(N, 8), 256, 0, stream>>>(xg, gat_w + (size_t)i * 16384,
                                                           nullptr, nullptr, nullptr, T, N, 0);
        gat_dots_k<<<cdiv(N * hh, 256), 256, 0, stream>>>(T, gat_asrc + i * 128, gat_adst + i * 128,
                                                          avv, bvv, N, hh);
        gat_k1<<<cdiv(N * hh, 256), 256, 0, stream>>>(rowptr, colidx, avv, bvv, mden, sinv, N, hh);
        gat_k2<<<gN32, 256, 0, stream>>>(rowptr, colidx, T, avv, bvv, mden, sinv,
                                         gat_b + i * 128, gat_bn_g + i * 128, gat_bn_b + i * 128,
                                         (i == 2) ? feat_imp : nullptr, xgn, N, hh, log2C);
        float* t = xg; xg = xgn; xgn = t;
    }
    linear_k<128, 64><<<cdiv(N, 16), 256, 0, stream>>>(xg, gat_c1w, gat_c1b, gat_cbn_g, gat_cbn_b, h1, N, 1);
    linear_k<64, 32><<<cdiv(N, 32), 256, 0, stream>>>(h1, gat_c2w, gat_c2b, nullptr, nullptr, h2, N, 1);
    linear_k<32, 128><<<cdiv(N, 8), 256, 0, stream>>>(h2, gat_c3w, gat_c3b, nullptr, nullptr, R, N, 0);

    // ---- fusion tail ----
    blend_k<<<gN32, 256, 0, stream>>>(GOUT, R, T, N * 32);
    linear_k<128, 64><<<cdiv(N, 16), 256, 0, stream>>>(T, fin_w, fin_b, fin_bn_g, fin_bn_b, h1, N, 1);
    fin2_k<<<cdiv(N, 256), 256, 0, stream>>>(h1, fin2_w, fin2_b, (float*)d_out, N);
}

// Round 3
// 788.677 us; speedup vs baseline: 1.3512x; 1.2178x over previous
//
#include <hip/hip_runtime.h>
#include <hip/hip_fp16.h>

// BN scale constant: 1/sqrt(1+1e-5)
#define RSQ_BN 0.9999950000374997f

__device__ __forceinline__ float leaky02(float x) { return x > 0.f ? x : 0.2f * x; }

__device__ __forceinline__ float4 ld4(const float* p) {
    return *reinterpret_cast<const float4*>(p);
}
__device__ __forceinline__ void st4(float* p, float4 v) {
    *reinterpret_cast<float4*>(p) = v;
}
__device__ __forceinline__ void st4(__half* p, float4 v) {
    union { uint2 u; __half2 h[2]; } pk;
    pk.h[0] = __floats2half2_rn(v.x, v.y);
    pk.h[1] = __floats2half2_rn(v.z, v.w);
    *reinterpret_cast<uint2*>(p) = pk.u;
}
__device__ __forceinline__ float4 h4f(uint2 u) {
    union { uint2 u; __half2 h[2]; } pk;
    pk.u = u;
    float2 lo = __half22float2(pk.h[0]);
    float2 hi = __half22float2(pk.h[1]);
    return make_float4(lo.x, lo.y, hi.x, hi.y);
}

// ---------------- CSR build ----------------

__global__ void zero_i32_k(int* __restrict__ p, int n) {
    int i = blockIdx.x * 256 + threadIdx.x;
    if (i < n) p[i] = 0;
}

__global__ void hist_k(const int* __restrict__ edst, int* __restrict__ cnt, int E, int EN) {
    int i = blockIdx.x * 256 + threadIdx.x;
    if (i >= EN) return;
    int d = (i < E) ? edst[i] : (i - E);   // self-loop for i>=E
    atomicAdd(&cnt[d], 1);
}

__global__ __launch_bounds__(256)
void scanA_k(const int* __restrict__ cnt, int* __restrict__ rowptr,
             int* __restrict__ bsum, int n) {
    __shared__ int sh[256];
    int t = threadIdx.x;
    int i = blockIdx.x * 256 + t;
    int v = (i < n) ? cnt[i] : 0;
    sh[t] = v;
    __syncthreads();
#pragma unroll
    for (int off = 1; off < 256; off <<= 1) {
        int u = 0;
        if (t >= off) u = sh[t - off];
        __syncthreads();
        sh[t] += u;
        __syncthreads();
    }
    if (i < n) rowptr[i] = sh[t] - v;
    if (t == 255) bsum[blockIdx.x] = sh[255];
}

__global__ __launch_bounds__(256)
void scanB_k(int* __restrict__ bsum, int nb) {
    __shared__ int sh[256];
    int t = threadIdx.x;
    int v = (t < nb) ? bsum[t] : 0;
    sh[t] = v;
    __syncthreads();
#pragma unroll
    for (int off = 1; off < 256; off <<= 1) {
        int u = 0;
        if (t >= off) u = sh[t - off];
        __syncthreads();
        sh[t] += u;
        __syncthreads();
    }
    if (t < nb) bsum[t] = sh[t] - v;
}

__global__ __launch_bounds__(256)
void scanC_k(const int* __restrict__ cnt, const int* __restrict__ bsum,
             int* __restrict__ rowptr, int* __restrict__ cursor,
             float* __restrict__ dis, int n, int EN) {
    int i = blockIdx.x * 256 + threadIdx.x;
    if (i < n) {
        int r = rowptr[i] + bsum[blockIdx.x];
        rowptr[i] = r;
        cursor[i] = r;
        dis[i] = rsqrtf((float)cnt[i]);
    }
    if (i == 0) rowptr[n] = EN;
}

__global__ void scatter_k(const int* __restrict__ esrc, const int* __restrict__ edst,
                          int* __restrict__ cursor, int* __restrict__ colidx, int E, int EN) {
    int i = blockIdx.x * 256 + threadIdx.x;
    if (i >= EN) return;
    int s, d;
    if (i < E) { s = esrc[i]; d = edst[i]; }
    else       { s = i - E; d = s; }
    int pos = atomicAdd(&cursor[d], 1);
    colidx[pos] = s;
}

// ---------------- dense linear (2-row register blocked) ----------------
// Y = act(X'@W + b), X' = X2 ? 0.6*X+0.4*X2 : X; bng => y = act(y)*(bng*RSQ_BN)+bnb.

template <int K, int M, typename OT>
__global__ __launch_bounds__(256)
void linear_k(const float* __restrict__ X, const float* __restrict__ X2,
              const float* __restrict__ W, const float* __restrict__ bias,
              const float* __restrict__ bng, const float* __restrict__ bnb,
              OT* __restrict__ Y, int n, int do_relu) {
    constexpr int CG = M / 4;        // col groups of 4
    constexpr int RPI = 256 / CG;    // rows per half-tile
    __shared__ float Ws[K * M];
    for (int i = threadIdx.x; i < K * M; i += 256) Ws[i] = W[i];
    __syncthreads();
    const int cg = threadIdx.x % CG;
    const int r = threadIdx.x / CG;
    const int c = cg * 4;
    const int row_a = blockIdx.x * (2 * RPI) + r;
    const int row_b = row_a + RPI;
    const bool va = row_a < n, vb = row_b < n;
    const float* xa = X + (size_t)(va ? row_a : 0) * K;
    const float* xb = X + (size_t)(vb ? row_b : 0) * K;
    const float* xa2 = X2 ? X2 + (size_t)(va ? row_a : 0) * K : nullptr;
    const float* xb2 = X2 ? X2 + (size_t)(vb ? row_b : 0) * K : nullptr;
    float ax = 0.f, ay = 0.f, az = 0.f, aw = 0.f;
    float bx = 0.f, by = 0.f, bz = 0.f, bw = 0.f;
#pragma unroll 4
    for (int k = 0; k < K; k += 4) {
        float4 va4 = ld4(xa + k);
        float4 vb4 = ld4(xb + k);
        if (X2) {
            float4 a2 = ld4(xa2 + k);
            float4 b2 = ld4(xb2 + k);
            va4 = make_float4(0.6f * va4.x + 0.4f * a2.x, 0.6f * va4.y + 0.4f * a2.y,
                              0.6f * va4.z + 0.4f * a2.z, 0.6f * va4.w + 0.4f * a2.w);
            vb4 = make_float4(0.6f * vb4.x + 0.4f * b2.x, 0.6f * vb4.y + 0.4f * b2.y,
                              0.6f * vb4.z + 0.4f * b2.z, 0.6f * vb4.w + 0.4f * b2.w);
        }
        const float* wp = Ws + k * M + c;
        float4 w0 = ld4(wp);
        float4 w1 = ld4(wp + M);
        float4 w2 = ld4(wp + 2 * M);
        float4 w3 = ld4(wp + 3 * M);
        ax += va4.x * w0.x + va4.y * w1.x + va4.z * w2.x + va4.w * w3.x;
        ay += va4.x * w0.y + va4.y * w1.y + va4.z * w2.y + va4.w * w3.y;
        az += va4.x * w0.z + va4.y * w1.z + va4.z * w2.z + va4.w * w3.z;
        aw += va4.x * w0.w + va4.y * w1.w + va4.z * w2.w + va4.w * w3.w;
        bx += vb4.x * w0.x + vb4.y * w1.x + vb4.z * w2.x + vb4.w * w3.x;
        by += vb4.x * w0.y + vb4.y * w1.y + vb4.z * w2.y + vb4.w * w3.y;
        bz += vb4.x * w0.z + vb4.y * w1.z + vb4.z * w2.z + vb4.w * w3.z;
        bw += vb4.x * w0.w + vb4.y * w1.w + vb4.z * w2.w + vb4.w * w3.w;
    }
    float c0 = bias ? bias[c] : 0.f, c1 = bias ? bias[c + 1] : 0.f;
    float c2 = bias ? bias[c + 2] : 0.f, c3 = bias ? bias[c + 3] : 0.f;
    ax += c0; ay += c1; az += c2; aw += c3;
    bx += c0; by += c1; bz += c2; bw += c3;
    if (do_relu) {
        ax = fmaxf(ax, 0.f); ay = fmaxf(ay, 0.f); az = fmaxf(az, 0.f); aw = fmaxf(aw, 0.f);
        bx = fmaxf(bx, 0.f); by = fmaxf(by, 0.f); bz = fmaxf(bz, 0.f); bw = fmaxf(bw, 0.f);
    }
    if (bng) {
        float g0 = bng[c] * RSQ_BN, g1 = bng[c + 1] * RSQ_BN;
        float g2 = bng[c + 2] * RSQ_BN, g3 = bng[c + 3] * RSQ_BN;
        float h0 = bnb[c], h1 = bnb[c + 1], h2 = bnb[c + 2], h3 = bnb[c + 3];
        ax = ax * g0 + h0; ay = ay * g1 + h1; az = az * g2 + h2; aw = aw * g3 + h3;
        bx = bx * g0 + h0; by = by * g1 + h1; bz = bz * g2 + h2; bw = bw * g3 + h3;
    }
    if (va) st4(Y + (size_t)row_a * M + c, make_float4(ax, ay, az, aw));
    if (vb) st4(Y + (size_t)row_b * M + c, make_float4(bx, by, bz, bw));
}

// ---------------- GCN aggregation (gather fp16 rows) + fused epilogue ----------------

__global__ __launch_bounds__(256)
void gcn_gather_k(const int* __restrict__ rowptr, const int* __restrict__ colidx,
                  const float* __restrict__ dis, const __half* __restrict__ T,
                  const float* __restrict__ bias, const float* __restrict__ bng,
                  const float* __restrict__ bnb, const float* __restrict__ res,
                  float* __restrict__ Y, int n) {
    int idx = blockIdx.x * 256 + threadIdx.x;
    int i = idx >> 5;
    if (i >= n) return;
    int c = (idx & 31) << 2;
    int p0 = rowptr[i], p1 = rowptr[i + 1];
    float ax = 0.f, ay = 0.f, az = 0.f, aw = 0.f;
    int p = p0;
    for (; p + 2 <= p1; p += 2) {
        int s0 = colidx[p], s1 = colidx[p + 1];
        float w0 = dis[s0], w1 = dis[s1];
        uint2 u0 = *reinterpret_cast<const uint2*>(T + (size_t)s0 * 128 + c);
        uint2 u1 = *reinterpret_cast<const uint2*>(T + (size_t)s1 * 128 + c);
        float4 v0 = h4f(u0), v1 = h4f(u1);
        ax += v0.x * w0 + v1.x * w1;
        ay += v0.y * w0 + v1.y * w1;
        az += v0.z * w0 + v1.z * w1;
        aw += v0.w * w0 + v1.w * w1;
    }
    if (p < p1) {
        int s0 = colidx[p];
        float w0 = dis[s0];
        float4 v0 = h4f(*reinterpret_cast<const uint2*>(T + (size_t)s0 * 128 + c));
        ax += v0.x * w0; ay += v0.y * w0; az += v0.z * w0; aw += v0.w * w0;
    }
    float di = dis[i];
    ax = ax * di + bias[c];
    ay = ay * di + bias[c + 1];
    az = az * di + bias[c + 2];
    aw = aw * di + bias[c + 3];
    ax = fmaxf(ax * (bng[c] * RSQ_BN) + bnb[c], 0.f);
    ay = fmaxf(ay * (bng[c + 1] * RSQ_BN) + bnb[c + 1], 0.f);
    az = fmaxf(az * (bng[c + 2] * RSQ_BN) + bnb[c + 2], 0.f);
    aw = fmaxf(aw * (bng[c + 3] * RSQ_BN) + bnb[c + 3], 0.f);
    if (res) {
        float4 rv = ld4(res + (size_t)i * 128 + c);
        ax += rv.x; ay += rv.y; az += rv.z; aw += rv.w;
    }
    st4(Y + (size_t)i * 128 + c, make_float4(ax, ay, az, aw));
}

// ---------------- GAT ----------------

__global__ void gat_dots_k(const __half* __restrict__ XH, const float* __restrict__ Asrc,
                           const float* __restrict__ Adst, float* __restrict__ av,
                           float* __restrict__ bv, int n, int hh) {
    int idx = blockIdx.x * 256 + threadIdx.x;
    if (idx >= n * hh) return;
    int i = idx / hh;
    int h = idx - i * hh;
    int C = 128 / hh;
    const __half* xr = XH + (size_t)i * 128 + h * C;
    const float* ap = Asrc + h * C;
    const float* bp = Adst + h * C;
    float sa = 0.f, sd = 0.f;
    for (int cc = 0; cc < C; cc += 4) {
        float4 v = h4f(*reinterpret_cast<const uint2*>(xr + cc));
        float4 a = ld4(ap + cc);
        float4 b = ld4(bp + cc);
        sa += v.x * a.x + v.y * a.y + v.z * a.z + v.w * a.w;
        sd += v.x * b.x + v.y * b.y + v.z * b.z + v.w * b.w;
    }
    av[idx] = sa;
    bv[idx] = sd;
}

__global__ void gat_k1(const int* __restrict__ rowptr, const int* __restrict__ colidx,
                       const float* __restrict__ av, const float* __restrict__ bv,
                       float* __restrict__ mden, float* __restrict__ sinv, int n, int hh) {
    int idx = blockIdx.x * 256 + threadIdx.x;
    if (idx >= n * hh) return;
    int i = idx / hh;
    int h = idx - i * hh;
    float ad = bv[idx];
    int p0 = rowptr[i], p1 = rowptr[i + 1];
    float m = -3.0e38f;
    for (int p = p0; p < p1; ++p) {
        float e = leaky02(av[colidx[p] * hh + h] + ad);
        m = fmaxf(m, e);
    }
    float s = 0.f;
    for (int p = p0; p < p1; ++p) {
        float e = leaky02(av[colidx[p] * hh + h] + ad);
        s += expf(e - m);
    }
    mden[idx] = m;
    sinv[idx] = 1.f / (s + 1e-16f);
}

__global__ __launch_bounds__(256)
void gat_k2(const int* __restrict__ rowptr, const int* __restrict__ colidx,
            const __half* __restrict__ XH, const float* __restrict__ av,
            const float* __restrict__ bv, const float* __restrict__ mden,
            const float* __restrict__ sinv, const float* __restrict__ bias,
            const float* __restrict__ bng, const float* __restrict__ bnb,
            const float* __restrict__ fimp, float* __restrict__ Y, int n, int hh, int log2C) {
    int idx = blockIdx.x * 256 + threadIdx.x;
    int i = idx >> 5;
    if (i >= n) return;
    int c = (idx & 31) << 2;
    int h = c >> log2C;
    float ad = bv[i * hh + h];
    float m = mden[i * hh + h];
    float si = sinv[i * hh + h];
    int p0 = rowptr[i], p1 = rowptr[i + 1];
    float ax = 0.f, ay = 0.f, az = 0.f, aw = 0.f;
    int p = p0;
    for (; p + 2 <= p1; p += 2) {
        int s0 = colidx[p], s1 = colidx[p + 1];
        float e0 = leaky02(av[s0 * hh + h] + ad);
        float e1 = leaky02(av[s1 * hh + h] + ad);
        float a0 = expf(e0 - m) * si;
        float a1 = expf(e1 - m) * si;
        uint2 u0 = *reinterpret_cast<const uint2*>(XH + (size_t)s0 * 128 + c);
        uint2 u1 = *reinterpret_cast<const uint2*>(XH + (size_t)s1 * 128 + c);
        float4 v0 = h4f(u0), v1 = h4f(u1);
        ax += v0.x * a0 + v1.x * a1;
        ay += v0.y * a0 + v1.y * a1;
        az += v0.z * a0 + v1.z * a1;
        aw += v0.w * a0 + v1.w * a1;
    }
    if (p < p1) {
        int s0 = colidx[p];
        float e0 = leaky02(av[s0 * hh + h] + ad);
        float a0 = expf(e0 - m) * si;
        float4 v0 = h4f(*reinterpret_cast<const uint2*>(XH + (size_t)s0 * 128 + c));
        ax += v0.x * a0; ay += v0.y * a0; az += v0.z * a0; aw += v0.w * a0;
    }
    ax += bias[c]; ay += bias[c + 1]; az += bias[c + 2]; aw += bias[c + 3];
    ax = ax * (bng[c] * RSQ_BN) + bnb[c];
    ay = ay * (bng[c + 1] * RSQ_BN) + bnb[c + 1];
    az = az * (bng[c + 2] * RSQ_BN) + bnb[c + 2];
    aw = aw * (bng[c + 3] * RSQ_BN) + bnb[c + 3];
    ax = ax > 0.f ? ax : expm1f(ax);
    ay = ay > 0.f ? ay : expm1f(ay);
    az = az > 0.f ? az : expm1f(az);
    aw = aw > 0.f ? aw : expm1f(aw);
    if (fimp) { ax *= fimp[c]; ay *= fimp[c + 1]; az *= fimp[c + 2]; aw *= fimp[c + 3]; }
    st4(Y + (size_t)i * 128 + c, make_float4(ax, ay, az, aw));
}

// ---------------- tail ----------------

__global__ void fin2_k(const float* __restrict__ H, const float* __restrict__ W,
                       const float* __restrict__ b, float* __restrict__ out, int n) {
    int i = blockIdx.x * 256 + threadIdx.x;
    if (i >= n) return;
    const float* hr = H + (size_t)i * 64;
    float o0 = b[0], o1 = b[1];
#pragma unroll
    for (int k = 0; k < 64; ++k) {
        float v = hr[k];
        o0 += v * W[2 * k];
        o1 += v * W[2 * k + 1];
    }
    out[2 * i] = o0;
    out[2 * i + 1] = o1;
}

// ---------------- host orchestration ----------------

static inline int cdiv(int a, int b) { return (a + b - 1) / b; }

extern "C" void kernel_launch(void* const* d_in, const int* in_sizes, int n_in,
                              void* d_out, int out_size, void* d_ws, size_t ws_size,
                              hipStream_t stream) {
    const float* x       = (const float*)d_in[0];
    const int*   ei      = (const int*)d_in[1];
    const float* gcn_in_w = (const float*)d_in[2];
    const float* gcn_in_b = (const float*)d_in[3];
    const float* gcn_res_w = (const float*)d_in[4];
    const float* gcn_res_b = (const float*)d_in[5];
    const float* gcn_w   = (const float*)d_in[6];
    const float* gcn_b   = (const float*)d_in[7];
    const float* gcn_bn_g = (const float*)d_in[8];
    const float* gcn_bn_b = (const float*)d_in[9];
    const float* gcn_c1w = (const float*)d_in[10];
    const float* gcn_c1b = (const float*)d_in[11];
    const float* gcn_c2w = (const float*)d_in[12];
    const float* gcn_c2b = (const float*)d_in[13];
    const float* gcn_c3w = (const float*)d_in[14];
    const float* gcn_c3b = (const float*)d_in[15];
    const float* gat_in_w = (const float*)d_in[16];
    const float* gat_in_b = (const float*)d_in[17];
    const float* gat_w   = (const float*)d_in[18];
    const float* gat_asrc = (const float*)d_in[19];
    const float* gat_adst = (const float*)d_in[20];
    const float* gat_b   = (const float*)d_in[21];
    const float* gat_bn_g = (const float*)d_in[22];
    const float* gat_bn_b = (const float*)d_in[23];
    const float* feat_imp = (const float*)d_in[24];
    const float* gat_c1w = (const float*)d_in[25];
    const float* gat_c1b = (const float*)d_in[26];
    const float* gat_cbn_g = (const float*)d_in[27];
    const float* gat_cbn_b = (const float*)d_in[28];
    const float* gat_c2w = (const float*)d_in[29];
    const float* gat_c2b = (const float*)d_in[30];
    const float* gat_c3w = (const float*)d_in[31];
    const float* gat_c3b = (const float*)d_in[32];
    const float* fin_w   = (const float*)d_in[33];
    const float* fin_b   = (const float*)d_in[34];
    const float* fin_bn_g = (const float*)d_in[35];
    const float* fin_bn_b = (const float*)d_in[36];
    const float* fin2_w  = (const float*)d_in[37];
    const float* fin2_b  = (const float*)d_in[38];

    const int N = in_sizes[0] / 64;
    const int E = in_sizes[1] / 2;
    const int EN = E + N;
    const int* esrc = ei;
    const int* edst = ei + E;

    // workspace carve (256B aligned)
    char* wp = (char*)d_ws;
    auto alloc = [&](size_t bytes) -> void* {
        void* p = (void*)wp;
        wp += (bytes + 255) & ~(size_t)255;
        return p;
    };
    int* cnt    = (int*)alloc((size_t)N * 4);
    int* rowptr = (int*)alloc((size_t)(N + 1) * 4);
    int* cursor = (int*)alloc((size_t)N * 4);
    int* bsum   = (int*)alloc((size_t)256 * 4);
    int* colidx = (int*)alloc((size_t)EN * 4);
    float* dis  = (float*)alloc((size_t)N * 4);
    float* A    = (float*)alloc((size_t)N * 128 * 4);
    float* B    = (float*)alloc((size_t)N * 128 * 4);
    float* R    = (float*)alloc((size_t)N * 128 * 4);
    __half* Th  = (__half*)alloc((size_t)N * 128 * 2);
    float* GOUT = (float*)alloc((size_t)N * 128 * 4);
    float* h1   = (float*)alloc((size_t)N * 64 * 4);
    float* h2   = (float*)alloc((size_t)N * 32 * 4);
    float* avv  = (float*)alloc((size_t)N * 4 * 4);
    float* bvv  = (float*)alloc((size_t)N * 4 * 4);
    float* mden = (float*)alloc((size_t)N * 4 * 4);
    float* sinv = (float*)alloc((size_t)N * 4 * 4);

    // ---- CSR build ----
    const int nScanB = cdiv(N, 256);
    zero_i32_k<<<cdiv(N, 256), 256, 0, stream>>>(cnt, N);
    hist_k<<<cdiv(EN, 256), 256, 0, stream>>>(edst, cnt, E, EN);
    scanA_k<<<nScanB, 256, 0, stream>>>(cnt, rowptr, bsum, N);
    scanB_k<<<1, 256, 0, stream>>>(bsum, nScanB);
    scanC_k<<<nScanB, 256, 0, stream>>>(cnt, bsum, rowptr, cursor, dis, N, EN);
    scatter_k<<<cdiv(EN, 256), 256, 0, stream>>>(esrc, edst, cursor, colidx, E, EN);

    const int gN32 = cdiv(N * 32, 256);
    const int g128 = cdiv(N, 16);   // M=128: 2*RPI=16 rows/block
    const int g64  = cdiv(N, 32);   // M=64
    const int g32  = cdiv(N, 64);   // M=32

    // ---- GCN branch ----
    linear_k<64, 128, float><<<g128, 256, 0, stream>>>(x, nullptr, gcn_in_w, gcn_in_b, nullptr, nullptr, A, N, 0);
    linear_k<64, 128, float><<<g128, 256, 0, stream>>>(x, nullptr, gcn_res_w, gcn_res_b, nullptr, nullptr, R, N, 0);
    float* cur = A;
    float* nxt = B;
    for (int i = 0; i < 3; ++i) {
        linear_k<128, 128, __half><<<g128, 256, 0, stream>>>(cur, nullptr, gcn_w + (size_t)i * 16384,
                                                             nullptr, nullptr, nullptr, Th, N, 0);
        gcn_gather_k<<<gN32, 256, 0, stream>>>(rowptr, colidx, dis, Th, gcn_b + i * 128,
                                               gcn_bn_g + i * 128, gcn_bn_b + i * 128,
                                               (i == 1) ? R : nullptr, nxt, N);
        float* t = cur; cur = nxt; nxt = t;
    }
    linear_k<128, 64, float><<<g64, 256, 0, stream>>>(cur, nullptr, gcn_c1w, gcn_c1b, nullptr, nullptr, h1, N, 1);
    linear_k<64, 32, float><<<g32, 256, 0, stream>>>(h1, nullptr, gcn_c2w, gcn_c2b, nullptr, nullptr, h2, N, 1);
    linear_k<32, 128, float><<<g128, 256, 0, stream>>>(h2, nullptr, gcn_c3w, gcn_c3b, nullptr, nullptr, GOUT, N, 0);

    // ---- GAT branch ----
    float* xg = A;
    float* xgn = B;
    linear_k<64, 128, float><<<g128, 256, 0, stream>>>(x, nullptr, gat_in_w, gat_in_b, nullptr, nullptr, xg, N, 0);
    const int heads_arr[3] = {4, 4, 1};
    for (int i = 0; i < 3; ++i) {
        int hh = heads_arr[i];
        int log2C = (hh == 4) ? 5 : 7;
        linear_k<128, 128, __half><<<g128, 256, 0, stream>>>(xg, nullptr, gat_w + (size_t)i * 16384,
                                                             nullptr, nullptr, nullptr, Th, N, 0);
        gat_dots_k<<<cdiv(N * hh, 256), 256, 0, stream>>>(Th, gat_asrc + i * 128, gat_adst + i * 128,
                                                          avv, bvv, N, hh);
        gat_k1<<<cdiv(N * hh, 256), 256, 0, stream>>>(rowptr, colidx, avv, bvv, mden, sinv, N, hh);
        gat_k2<<<gN32, 256, 0, stream>>>(rowptr, colidx, Th, avv, bvv, mden, sinv,
                                         gat_b + i * 128, gat_bn_g + i * 128, gat_bn_b + i * 128,
                                         (i == 2) ? feat_imp : nullptr, xgn, N, hh, log2C);
        float* t = xg; xg = xgn; xgn = t;
    }
    linear_k<128, 64, float><<<g64, 256, 0, stream>>>(xg, nullptr, gat_c1w, gat_c1b, gat_cbn_g, gat_cbn_b, h1, N, 1);
    linear_k<64, 32, float><<<g32, 256, 0, stream>>>(h1, nullptr, gat_c2w, gat_c2b, nullptr, nullptr, h2, N, 1);
    linear_k<32, 128, float><<<g128, 256, 0, stream>>>(h2, nullptr, gat_c3w, gat_c3b, nullptr, nullptr, R, N, 0);

    // ---- fusion tail (blend fused into the linear) ----
    linear_k<128, 64, float><<<g64, 256, 0, stream>>>(GOUT, R, fin_w, fin_b, fin_bn_g, fin_bn_b, h1, N, 1);
    fin2_k<<<cdiv(N, 256), 256, 0, stream>>>(h1, fin2_w, fin2_b, (float*)d_out, N);
}

// Round 4
// 693.858 us; speedup vs baseline: 1.5358x; 1.1367x over previous
//
#include <hip/hip_runtime.h>
#include <hip/hip_fp16.h>

// BN scale constant: 1/sqrt(1+1e-5)
#define RSQ_BN 0.9999950000374997f

__device__ __forceinline__ float leaky02(float x) { return x > 0.f ? x : 0.2f * x; }

__device__ __forceinline__ float4 ld4(const float* p) {
    return *reinterpret_cast<const float4*>(p);
}
__device__ __forceinline__ void st4(float* p, float4 v) {
    *reinterpret_cast<float4*>(p) = v;
}
__device__ __forceinline__ void st4(__half* p, float4 v) {
    union { uint2 u; __half2 h[2]; } pk;
    pk.h[0] = __floats2half2_rn(v.x, v.y);
    pk.h[1] = __floats2half2_rn(v.z, v.w);
    *reinterpret_cast<uint2*>(p) = pk.u;
}
__device__ __forceinline__ float4 h4f(uint2 u) {
    union { uint2 u; __half2 h[2]; } pk;
    pk.u = u;
    float2 lo = __half22float2(pk.h[0]);
    float2 hi = __half22float2(pk.h[1]);
    return make_float4(lo.x, lo.y, hi.x, hi.y);
}

// ---------------- CSR build ----------------

__global__ void zero_i32_k(int* __restrict__ p, int n) {
    int i = blockIdx.x * 256 + threadIdx.x;
    if (i < n) p[i] = 0;
}

__global__ void hist_k(const int* __restrict__ edst, int* __restrict__ cnt, int E, int EN) {
    int i = blockIdx.x * 256 + threadIdx.x;
    if (i >= EN) return;
    int d = (i < E) ? edst[i] : (i - E);   // self-loop for i>=E
    atomicAdd(&cnt[d], 1);
}

__global__ __launch_bounds__(256)
void scanA_k(const int* __restrict__ cnt, int* __restrict__ rowptr,
             int* __restrict__ bsum, int n) {
    __shared__ int sh[256];
    int t = threadIdx.x;
    int i = blockIdx.x * 256 + t;
    int v = (i < n) ? cnt[i] : 0;
    sh[t] = v;
    __syncthreads();
#pragma unroll
    for (int off = 1; off < 256; off <<= 1) {
        int u = 0;
        if (t >= off) u = sh[t - off];
        __syncthreads();
        sh[t] += u;
        __syncthreads();
    }
    if (i < n) rowptr[i] = sh[t] - v;
    if (t == 255) bsum[blockIdx.x] = sh[255];
}

__global__ __launch_bounds__(256)
void scanB_k(int* __restrict__ bsum, int nb) {
    __shared__ int sh[256];
    int t = threadIdx.x;
    int v = (t < nb) ? bsum[t] : 0;
    sh[t] = v;
    __syncthreads();
#pragma unroll
    for (int off = 1; off < 256; off <<= 1) {
        int u = 0;
        if (t >= off) u = sh[t - off];
        __syncthreads();
        sh[t] += u;
        __syncthreads();
    }
    if (t < nb) bsum[t] = sh[t] - v;
}

__global__ __launch_bounds__(256)
void scanC_k(const int* __restrict__ cnt, const int* __restrict__ bsum,
             int* __restrict__ rowptr, int* __restrict__ cursor,
             float* __restrict__ dis, int n, int EN) {
    int i = blockIdx.x * 256 + threadIdx.x;
    if (i < n) {
        int r = rowptr[i] + bsum[blockIdx.x];
        rowptr[i] = r;
        cursor[i] = r;
        dis[i] = rsqrtf((float)cnt[i]);
    }
    if (i == 0) rowptr[n] = EN;
}

__global__ void scatter_k(const int* __restrict__ esrc, const int* __restrict__ edst,
                          int* __restrict__ cursor, int* __restrict__ colidx, int E, int EN) {
    int i = blockIdx.x * 256 + threadIdx.x;
    if (i >= EN) return;
    int s, d;
    if (i < E) { s = esrc[i]; d = edst[i]; }
    else       { s = i - E; d = s; }
    int pos = atomicAdd(&cursor[d], 1);
    colidx[pos] = s;
}

// ---------------- dense linear (2-row register blocked, fused epilogues) ----------------
// Y = act(X'@W + b), X' = X2 ? 0.6*X+0.4*X2 : X; bng => y = act(y)*(bng*RSQ_BN)+bnb.
// EPI=1 (M=128): also emit per-head dots av=y.asrc, bv=y.adst (GAT attention inputs).
// EPI=2 (M=64):  skip Y store; emit out2[row,2] = y @ w2 + b2 (final classifier).

template <int K, int M, typename OT, int EPI>
__global__ __launch_bounds__(256)
void linear_k(const float* __restrict__ X, const float* __restrict__ X2,
              const float* __restrict__ W, const float* __restrict__ bias,
              const float* __restrict__ bng, const float* __restrict__ bnb,
              OT* __restrict__ Y, int n, int do_relu,
              const float* __restrict__ asrc, const float* __restrict__ adst,
              float* __restrict__ avp, float* __restrict__ bvp, int hh,
              const float* __restrict__ w2, const float* __restrict__ b2,
              float* __restrict__ out2) {
    constexpr int CG = M / 4;        // col groups of 4
    constexpr int RPI = 256 / CG;    // rows per half-tile
    __shared__ float Ws[K * M];
    for (int i = threadIdx.x; i < K * M; i += 256) Ws[i] = W[i];
    __syncthreads();
    const int cg = threadIdx.x % CG;
    const int r = threadIdx.x / CG;
    const int c = cg * 4;
    const int row_a = blockIdx.x * (2 * RPI) + r;
    const int row_b = row_a + RPI;
    const bool va = row_a < n, vb = row_b < n;
    const float* xa = X + (size_t)(va ? row_a : 0) * K;
    const float* xb = X + (size_t)(vb ? row_b : 0) * K;
    const float* xa2 = X2 ? X2 + (size_t)(va ? row_a : 0) * K : nullptr;
    const float* xb2 = X2 ? X2 + (size_t)(vb ? row_b : 0) * K : nullptr;
    float ax = 0.f, ay = 0.f, az = 0.f, aw = 0.f;
    float bx = 0.f, by = 0.f, bz = 0.f, bw = 0.f;
#pragma unroll 4
    for (int k = 0; k < K; k += 4) {
        float4 va4 = ld4(xa + k);
        float4 vb4 = ld4(xb + k);
        if (X2) {
            float4 a2 = ld4(xa2 + k);
            float4 b2v = ld4(xb2 + k);
            va4 = make_float4(0.6f * va4.x + 0.4f * a2.x, 0.6f * va4.y + 0.4f * a2.y,
                              0.6f * va4.z + 0.4f * a2.z, 0.6f * va4.w + 0.4f * a2.w);
            vb4 = make_float4(0.6f * vb4.x + 0.4f * b2v.x, 0.6f * vb4.y + 0.4f * b2v.y,
                              0.6f * vb4.z + 0.4f * b2v.z, 0.6f * vb4.w + 0.4f * b2v.w);
        }
        const float* wp = Ws + k * M + c;
        float4 w0 = ld4(wp);
        float4 w1 = ld4(wp + M);
        float4 w2v = ld4(wp + 2 * M);
        float4 w3 = ld4(wp + 3 * M);
        ax += va4.x * w0.x + va4.y * w1.x + va4.z * w2v.x + va4.w * w3.x;
        ay += va4.x * w0.y + va4.y * w1.y + va4.z * w2v.y + va4.w * w3.y;
        az += va4.x * w0.z + va4.y * w1.z + va4.z * w2v.z + va4.w * w3.z;
        aw += va4.x * w0.w + va4.y * w1.w + va4.z * w2v.w + va4.w * w3.w;
        bx += vb4.x * w0.x + vb4.y * w1.x + vb4.z * w2v.x + vb4.w * w3.x;
        by += vb4.x * w0.y + vb4.y * w1.y + vb4.z * w2v.y + vb4.w * w3.y;
        bz += vb4.x * w0.z + vb4.y * w1.z + vb4.z * w2v.z + vb4.w * w3.z;
        bw += vb4.x * w0.w + vb4.y * w1.w + vb4.z * w2v.w + vb4.w * w3.w;
    }
    float c0 = bias ? bias[c] : 0.f, c1 = bias ? bias[c + 1] : 0.f;
    float c2 = bias ? bias[c + 2] : 0.f, c3 = bias ? bias[c + 3] : 0.f;
    ax += c0; ay += c1; az += c2; aw += c3;
    bx += c0; by += c1; bz += c2; bw += c3;
    if (do_relu) {
        ax = fmaxf(ax, 0.f); ay = fmaxf(ay, 0.f); az = fmaxf(az, 0.f); aw = fmaxf(aw, 0.f);
        bx = fmaxf(bx, 0.f); by = fmaxf(by, 0.f); bz = fmaxf(bz, 0.f); bw = fmaxf(bw, 0.f);
    }
    if (bng) {
        float g0 = bng[c] * RSQ_BN, g1 = bng[c + 1] * RSQ_BN;
        float g2 = bng[c + 2] * RSQ_BN, g3 = bng[c + 3] * RSQ_BN;
        float h0 = bnb[c], h1 = bnb[c + 1], h2 = bnb[c + 2], h3 = bnb[c + 3];
        ax = ax * g0 + h0; ay = ay * g1 + h1; az = az * g2 + h2; aw = aw * g3 + h3;
        bx = bx * g0 + h0; by = by * g1 + h1; bz = bz * g2 + h2; bw = bw * g3 + h3;
    }
    if constexpr (EPI == 1) {
        // GAT attention dots: reduce y.asrc / y.adst per head across 32/hh lanes.
        float sa = ax * asrc[c] + ay * asrc[c + 1] + az * asrc[c + 2] + aw * asrc[c + 3];
        float sd = ax * adst[c] + ay * adst[c + 1] + az * adst[c + 2] + aw * adst[c + 3];
        float ta = bx * asrc[c] + by * asrc[c + 1] + bz * asrc[c + 2] + bw * asrc[c + 3];
        float td = bx * adst[c] + by * adst[c + 1] + bz * adst[c + 2] + bw * adst[c + 3];
        int gw = 32 / hh;   // lanes per head group (8 or 32), group-aligned in cg
        for (int off = 1; off < gw; off <<= 1) {
            sa += __shfl_xor(sa, off);
            sd += __shfl_xor(sd, off);
            ta += __shfl_xor(ta, off);
            td += __shfl_xor(td, off);
        }
        if ((cg & (gw - 1)) == 0) {
            int h = cg / gw;
            if (va) { avp[row_a * hh + h] = sa; bvp[row_a * hh + h] = sd; }
            if (vb) { avp[row_b * hh + h] = ta; bvp[row_b * hh + h] = td; }
        }
    }
    if constexpr (EPI == 2) {
        // final classifier: out2[row] = y @ w2 + b2 (w2: [M,2])
        float p0 = ax * w2[2 * c] + ay * w2[2 * c + 2] + az * w2[2 * c + 4] + aw * w2[2 * c + 6];
        float p1 = ax * w2[2 * c + 1] + ay * w2[2 * c + 3] + az * w2[2 * c + 5] + aw * w2[2 * c + 7];
        float q0 = bx * w2[2 * c] + by * w2[2 * c + 2] + bz * w2[2 * c + 4] + bw * w2[2 * c + 6];
        float q1 = bx * w2[2 * c + 1] + by * w2[2 * c + 3] + bz * w2[2 * c + 5] + bw * w2[2 * c + 7];
        for (int off = 1; off < CG; off <<= 1) {
            p0 += __shfl_xor(p0, off);
            p1 += __shfl_xor(p1, off);
            q0 += __shfl_xor(q0, off);
            q1 += __shfl_xor(q1, off);
        }
        if (cg == 0) {
            if (va) { out2[row_a * 2] = p0 + b2[0]; out2[row_a * 2 + 1] = p1 + b2[1]; }
            if (vb) { out2[row_b * 2] = q0 + b2[0]; out2[row_b * 2 + 1] = q1 + b2[1]; }
        }
    } else {
        if (va) st4(Y + (size_t)row_a * M + c, make_float4(ax, ay, az, aw));
        if (vb) st4(Y + (size_t)row_b * M + c, make_float4(bx, by, bz, bw));
    }
}

// ---------------- GCN aggregation (gather fp16 rows, 4x unroll) ----------------

__global__ __launch_bounds__(256)
void gcn_gather_k(const int* __restrict__ rowptr, const int* __restrict__ colidx,
                  const float* __restrict__ dis, const __half* __restrict__ T,
                  const float* __restrict__ bias, const float* __restrict__ bng,
                  const float* __restrict__ bnb, const float* __restrict__ res,
                  float* __restrict__ Y, int n) {
    int idx = blockIdx.x * 256 + threadIdx.x;
    int i = idx >> 5;
    if (i >= n) return;
    int c = (idx & 31) << 2;
    int p0 = rowptr[i], p1 = rowptr[i + 1];
    float ax = 0.f, ay = 0.f, az = 0.f, aw = 0.f;
    int p = p0;
    for (; p + 4 <= p1; p += 4) {
        int s0 = colidx[p], s1 = colidx[p + 1], s2 = colidx[p + 2], s3 = colidx[p + 3];
        float w0 = dis[s0], w1 = dis[s1], w2 = dis[s2], w3 = dis[s3];
        uint2 u0 = *reinterpret_cast<const uint2*>(T + (size_t)s0 * 128 + c);
        uint2 u1 = *reinterpret_cast<const uint2*>(T + (size_t)s1 * 128 + c);
        uint2 u2 = *reinterpret_cast<const uint2*>(T + (size_t)s2 * 128 + c);
        uint2 u3 = *reinterpret_cast<const uint2*>(T + (size_t)s3 * 128 + c);
        float4 v0 = h4f(u0), v1 = h4f(u1), v2 = h4f(u2), v3 = h4f(u3);
        ax += v0.x * w0 + v1.x * w1 + v2.x * w2 + v3.x * w3;
        ay += v0.y * w0 + v1.y * w1 + v2.y * w2 + v3.y * w3;
        az += v0.z * w0 + v1.z * w1 + v2.z * w2 + v3.z * w3;
        aw += v0.w * w0 + v1.w * w1 + v2.w * w2 + v3.w * w3;
    }
    for (; p < p1; ++p) {
        int s0 = colidx[p];
        float w0 = dis[s0];
        float4 v0 = h4f(*reinterpret_cast<const uint2*>(T + (size_t)s0 * 128 + c));
        ax += v0.x * w0; ay += v0.y * w0; az += v0.z * w0; aw += v0.w * w0;
    }
    float di = dis[i];
    ax = ax * di + bias[c];
    ay = ay * di + bias[c + 1];
    az = az * di + bias[c + 2];
    aw = aw * di + bias[c + 3];
    ax = fmaxf(ax * (bng[c] * RSQ_BN) + bnb[c], 0.f);
    ay = fmaxf(ay * (bng[c + 1] * RSQ_BN) + bnb[c + 1], 0.f);
    az = fmaxf(az * (bng[c + 2] * RSQ_BN) + bnb[c + 2], 0.f);
    aw = fmaxf(aw * (bng[c + 3] * RSQ_BN) + bnb[c + 3], 0.f);
    if (res) {
        float4 rv = ld4(res + (size_t)i * 128 + c);
        ax += rv.x; ay += rv.y; az += rv.z; aw += rv.w;
    }
    st4(Y + (size_t)i * 128 + c, make_float4(ax, ay, az, aw));
}

// ---------------- GAT aggregation: online softmax + weighted gather ----------------

__global__ __launch_bounds__(256)
void gat_k2(const int* __restrict__ rowptr, const int* __restrict__ colidx,
            const __half* __restrict__ XH, const float* __restrict__ avp,
            const float* __restrict__ bvp, const float* __restrict__ bias,
            const float* __restrict__ bng, const float* __restrict__ bnb,
            const float* __restrict__ fimp, float* __restrict__ Y, int n, int hh, int log2C) {
    int idx = blockIdx.x * 256 + threadIdx.x;
    int i = idx >> 5;
    if (i >= n) return;
    int c = (idx & 31) << 2;
    int h = c >> log2C;
    float ad = bvp[i * hh + h];
    int p0 = rowptr[i], p1 = rowptr[i + 1];
    float m = -3.0e38f, s = 0.f;
    float ax = 0.f, ay = 0.f, az = 0.f, aw = 0.f;
    int p = p0;
    for (; p + 4 <= p1; p += 4) {
        int s0 = colidx[p], s1 = colidx[p + 1], s2 = colidx[p + 2], s3 = colidx[p + 3];
        float e0 = leaky02(avp[s0 * hh + h] + ad);
        float e1 = leaky02(avp[s1 * hh + h] + ad);
        float e2 = leaky02(avp[s2 * hh + h] + ad);
        float e3 = leaky02(avp[s3 * hh + h] + ad);
        uint2 u0 = *reinterpret_cast<const uint2*>(XH + (size_t)s0 * 128 + c);
        uint2 u1 = *reinterpret_cast<const uint2*>(XH + (size_t)s1 * 128 + c);
        uint2 u2 = *reinterpret_cast<const uint2*>(XH + (size_t)s2 * 128 + c);
        uint2 u3 = *reinterpret_cast<const uint2*>(XH + (size_t)s3 * 128 + c);
        float mn = fmaxf(m, fmaxf(fmaxf(e0, e1), fmaxf(e2, e3)));
        float scale = expf(m - mn);
        float w0 = expf(e0 - mn), w1 = expf(e1 - mn);
        float w2 = expf(e2 - mn), w3 = expf(e3 - mn);
        s = s * scale + ((w0 + w1) + (w2 + w3));
        float4 v0 = h4f(u0), v1 = h4f(u1), v2 = h4f(u2), v3 = h4f(u3);
        ax = ax * scale + v0.x * w0 + v1.x * w1 + v2.x * w2 + v3.x * w3;
        ay = ay * scale + v0.y * w0 + v1.y * w1 + v2.y * w2 + v3.y * w3;
        az = az * scale + v0.z * w0 + v1.z * w1 + v2.z * w2 + v3.z * w3;
        aw = aw * scale + v0.w * w0 + v1.w * w1 + v2.w * w2 + v3.w * w3;
        m = mn;
    }
    for (; p < p1; ++p) {
        int s0 = colidx[p];
        float e0 = leaky02(avp[s0 * hh + h] + ad);
        float mn = fmaxf(m, e0);
        float scale = expf(m - mn);
        float w0 = expf(e0 - mn);
        s = s * scale + w0;
        float4 v0 = h4f(*reinterpret_cast<const uint2*>(XH + (size_t)s0 * 128 + c));
        ax = ax * scale + v0.x * w0;
        ay = ay * scale + v0.y * w0;
        az = az * scale + v0.z * w0;
        aw = aw * scale + v0.w * w0;
        m = mn;
    }
    float si = 1.f / (s + 1e-16f);
    ax = ax * si + bias[c];
    ay = ay * si + bias[c + 1];
    az = az * si + bias[c + 2];
    aw = aw * si + bias[c + 3];
    ax = ax * (bng[c] * RSQ_BN) + bnb[c];
    ay = ay * (bng[c + 1] * RSQ_BN) + bnb[c + 1];
    az = az * (bng[c + 2] * RSQ_BN) + bnb[c + 2];
    aw = aw * (bng[c + 3] * RSQ_BN) + bnb[c + 3];
    ax = ax > 0.f ? ax : expm1f(ax);
    ay = ay > 0.f ? ay : expm1f(ay);
    az = az > 0.f ? az : expm1f(az);
    aw = aw > 0.f ? aw : expm1f(aw);
    if (fimp) { ax *= fimp[c]; ay *= fimp[c + 1]; az *= fimp[c + 2]; aw *= fimp[c + 3]; }
    st4(Y + (size_t)i * 128 + c, make_float4(ax, ay, az, aw));
}

// ---------------- host orchestration ----------------

static inline int cdiv(int a, int b) { return (a + b - 1) / b; }

extern "C" void kernel_launch(void* const* d_in, const int* in_sizes, int n_in,
                              void* d_out, int out_size, void* d_ws, size_t ws_size,
                              hipStream_t stream) {
    const float* x       = (const float*)d_in[0];
    const int*   ei      = (const int*)d_in[1];
    const float* gcn_in_w = (const float*)d_in[2];
    const float* gcn_in_b = (const float*)d_in[3];
    const float* gcn_res_w = (const float*)d_in[4];
    const float* gcn_res_b = (const float*)d_in[5];
    const float* gcn_w   = (const float*)d_in[6];
    const float* gcn_b   = (const float*)d_in[7];
    const float* gcn_bn_g = (const float*)d_in[8];
    const float* gcn_bn_b = (const float*)d_in[9];
    const float* gcn_c1w = (const float*)d_in[10];
    const float* gcn_c1b = (const float*)d_in[11];
    const float* gcn_c2w = (const float*)d_in[12];
    const float* gcn_c2b = (const float*)d_in[13];
    const float* gcn_c3w = (const float*)d_in[14];
    const float* gcn_c3b = (const float*)d_in[15];
    const float* gat_in_w = (const float*)d_in[16];
    const float* gat_in_b = (const float*)d_in[17];
    const float* gat_w   = (const float*)d_in[18];
    const float* gat_asrc = (const float*)d_in[19];
    const float* gat_adst = (const float*)d_in[20];
    const float* gat_b   = (const float*)d_in[21];
    const float* gat_bn_g = (const float*)d_in[22];
    const float* gat_bn_b = (const float*)d_in[23];
    const float* feat_imp = (const float*)d_in[24];
    const float* gat_c1w = (const float*)d_in[25];
    const float* gat_c1b = (const float*)d_in[26];
    const float* gat_cbn_g = (const float*)d_in[27];
    const float* gat_cbn_b = (const float*)d_in[28];
    const float* gat_c2w = (const float*)d_in[29];
    const float* gat_c2b = (const float*)d_in[30];
    const float* gat_c3w = (const float*)d_in[31];
    const float* gat_c3b = (const float*)d_in[32];
    const float* fin_w   = (const float*)d_in[33];
    const float* fin_b   = (const float*)d_in[34];
    const float* fin_bn_g = (const float*)d_in[35];
    const float* fin_bn_b = (const float*)d_in[36];
    const float* fin2_w  = (const float*)d_in[37];
    const float* fin2_b  = (const float*)d_in[38];

    const int N = in_sizes[0] / 64;
    const int E = in_sizes[1] / 2;
    const int EN = E + N;
    const int* esrc = ei;
    const int* edst = ei + E;

    // workspace carve (256B aligned)
    char* wp = (char*)d_ws;
    auto alloc = [&](size_t bytes) -> void* {
        void* p = (void*)wp;
        wp += (bytes + 255) & ~(size_t)255;
        return p;
    };
    int* cnt    = (int*)alloc((size_t)N * 4);
    int* rowptr = (int*)alloc((size_t)(N + 1) * 4);
    int* cursor = (int*)alloc((size_t)N * 4);
    int* bsum   = (int*)alloc((size_t)256 * 4);
    int* colidx = (int*)alloc((size_t)EN * 4);
    float* dis  = (float*)alloc((size_t)N * 4);
    float* A    = (float*)alloc((size_t)N * 128 * 4);
    float* B    = (float*)alloc((size_t)N * 128 * 4);
    float* R    = (float*)alloc((size_t)N * 128 * 4);
    __half* Th  = (__half*)alloc((size_t)N * 128 * 2);
    float* GOUT = (float*)alloc((size_t)N * 128 * 4);
    float* h1   = (float*)alloc((size_t)N * 64 * 4);
    float* h2   = (float*)alloc((size_t)N * 32 * 4);
    float* avv  = (float*)alloc((size_t)N * 4 * 4);
    float* bvv  = (float*)alloc((size_t)N * 4 * 4);

    // ---- CSR build ----
    const int nScanB = cdiv(N, 256);
    zero_i32_k<<<cdiv(N, 256), 256, 0, stream>>>(cnt, N);
    hist_k<<<cdiv(EN, 256), 256, 0, stream>>>(edst, cnt, E, EN);
    scanA_k<<<nScanB, 256, 0, stream>>>(cnt, rowptr, bsum, N);
    scanB_k<<<1, 256, 0, stream>>>(bsum, nScanB);
    scanC_k<<<nScanB, 256, 0, stream>>>(cnt, bsum, rowptr, cursor, dis, N, EN);
    scatter_k<<<cdiv(EN, 256), 256, 0, stream>>>(esrc, edst, cursor, colidx, E, EN);

    const int gN32 = cdiv(N * 32, 256);
    const int g128 = cdiv(N, 16);   // M=128: 16 rows/block
    const int g64  = cdiv(N, 32);   // M=64: 32 rows/block
    const int g32  = cdiv(N, 64);   // M=32

#define LK(Kk, Mm, OT, EPI) linear_k<Kk, Mm, OT, EPI><<<(Mm == 128 ? g128 : (Mm == 64 ? g64 : g32)), 256, 0, stream>>>

    // ---- GCN branch ----
    LK(64, 128, float, 0)(x, nullptr, gcn_in_w, gcn_in_b, nullptr, nullptr, A, N, 0,
                          nullptr, nullptr, nullptr, nullptr, 0, nullptr, nullptr, nullptr);
    LK(64, 128, float, 0)(x, nullptr, gcn_res_w, gcn_res_b, nullptr, nullptr, R, N, 0,
                          nullptr, nullptr, nullptr, nullptr, 0, nullptr, nullptr, nullptr);
    float* cur = A;
    float* nxt = B;
    for (int i = 0; i < 3; ++i) {
        LK(128, 128, __half, 0)(cur, nullptr, gcn_w + (size_t)i * 16384, nullptr, nullptr, nullptr,
                                Th, N, 0, nullptr, nullptr, nullptr, nullptr, 0, nullptr, nullptr, nullptr);
        gcn_gather_k<<<gN32, 256, 0, stream>>>(rowptr, colidx, dis, Th, gcn_b + i * 128,
                                               gcn_bn_g + i * 128, gcn_bn_b + i * 128,
                                               (i == 1) ? R : nullptr, nxt, N);
        float* t = cur; cur = nxt; nxt = t;
    }
    LK(128, 64, float, 0)(cur, nullptr, gcn_c1w, gcn_c1b, nullptr, nullptr, h1, N, 1,
                          nullptr, nullptr, nullptr, nullptr, 0, nullptr, nullptr, nullptr);
    LK(64, 32, float, 0)(h1, nullptr, gcn_c2w, gcn_c2b, nullptr, nullptr, h2, N, 1,
                         nullptr, nullptr, nullptr, nullptr, 0, nullptr, nullptr, nullptr);
    LK(32, 128, float, 0)(h2, nullptr, gcn_c3w, gcn_c3b, nullptr, nullptr, GOUT, N, 0,
                          nullptr, nullptr, nullptr, nullptr, 0, nullptr, nullptr, nullptr);

    // ---- GAT branch ----
    float* xg = A;
    float* xgn = B;
    LK(64, 128, float, 0)(x, nullptr, gat_in_w, gat_in_b, nullptr, nullptr, xg, N, 0,
                          nullptr, nullptr, nullptr, nullptr, 0, nullptr, nullptr, nullptr);
    const int heads_arr[3] = {4, 4, 1};
    for (int i = 0; i < 3; ++i) {
        int hh = heads_arr[i];
        int log2C = (hh == 4) ? 5 : 7;
        LK(128, 128, __half, 1)(xg, nullptr, gat_w + (size_t)i * 16384, nullptr, nullptr, nullptr,
                                Th, N, 0, gat_asrc + i * 128, gat_adst + i * 128, avv, bvv, hh,
                                nullptr, nullptr, nullptr);
        gat_k2<<<gN32, 256, 0, stream>>>(rowptr, colidx, Th, avv, bvv,
                                         gat_b + i * 128, gat_bn_g + i * 128, gat_bn_b + i * 128,
                                         (i == 2) ? feat_imp : nullptr, xgn, N, hh, log2C);
        float* t = xg; xg = xgn; xgn = t;
    }
    LK(128, 64, float, 0)(xg, nullptr, gat_c1w, gat_c1b, gat_cbn_g, gat_cbn_b, h1, N, 1,
                          nullptr, nullptr, nullptr, nullptr, 0, nullptr, nullptr, nullptr);
    LK(64, 32, float, 0)(h1, nullptr, gat_c2w, gat_c2b, nullptr, nullptr, h2, N, 1,
                         nullptr, nullptr, nullptr, nullptr, 0, nullptr, nullptr, nullptr);
    LK(32, 128, float, 0)(h2, nullptr, gat_c3w, gat_c3b, nullptr, nullptr, R, N, 0,
                          nullptr, nullptr, nullptr, nullptr, 0, nullptr, nullptr, nullptr);

    // ---- fusion tail: blend + fin linear + classifier, all in one kernel ----
    LK(128, 64, float, 2)(GOUT, R, fin_w, fin_b, fin_bn_g, fin_bn_b, (float*)nullptr, N, 1,
                          nullptr, nullptr, nullptr, nullptr, 0, fin2_w, fin2_b, (float*)d_out);
#undef LK
}

// Round 5
// 594.628 us; speedup vs baseline: 1.7921x; 1.1669x over previous
//
#include <hip/hip_runtime.h>
#include <hip/hip_fp16.h>

// BN scale constant: 1/sqrt(1+1e-5)
#define RSQ_BN 0.9999950000374997f

__device__ __forceinline__ float leaky02(float x) { return x > 0.f ? x : 0.2f * x; }

__device__ __forceinline__ float4 ld4(const float* p) {
    return *reinterpret_cast<const float4*>(p);
}
__device__ __forceinline__ void st4(float* p, float4 v) {
    *reinterpret_cast<float4*>(p) = v;
}
__device__ __forceinline__ void sth4(__half* p, float4 v) {
    union { uint2 u; __half2 h[2]; } pk;
    pk.h[0] = __floats2half2_rn(v.x, v.y);
    pk.h[1] = __floats2half2_rn(v.z, v.w);
    *reinterpret_cast<uint2*>(p) = pk.u;
}
__device__ __forceinline__ float4 h4f(uint2 u) {
    union { uint2 u; __half2 h[2]; } pk;
    pk.u = u;
    float2 lo = __half22float2(pk.h[0]);
    float2 hi = __half22float2(pk.h[1]);
    return make_float4(lo.x, lo.y, hi.x, hi.y);
}
__device__ __forceinline__ float4 f4z() { return make_float4(0.f, 0.f, 0.f, 0.f); }

// ---------------- CSR build ----------------

__global__ void zero_i32_k(int* __restrict__ p, int n) {
    int i = blockIdx.x * 256 + threadIdx.x;
    if (i < n) p[i] = 0;
}

__global__ void hist_k(const int* __restrict__ edst, int* __restrict__ cnt, int E, int EN) {
    int i = blockIdx.x * 256 + threadIdx.x;
    if (i >= EN) return;
    int d = (i < E) ? edst[i] : (i - E);   // self-loop for i>=E
    atomicAdd(&cnt[d], 1);
}

__global__ __launch_bounds__(256)
void scanA_k(const int* __restrict__ cnt, int* __restrict__ rowptr,
             int* __restrict__ bsum, int n) {
    __shared__ int sh[256];
    int t = threadIdx.x;
    int i = blockIdx.x * 256 + t;
    int v = (i < n) ? cnt[i] : 0;
    sh[t] = v;
    __syncthreads();
#pragma unroll
    for (int off = 1; off < 256; off <<= 1) {
        int u = 0;
        if (t >= off) u = sh[t - off];
        __syncthreads();
        sh[t] += u;
        __syncthreads();
    }
    if (i < n) rowptr[i] = sh[t] - v;
    if (t == 255) bsum[blockIdx.x] = sh[255];
}

__global__ __launch_bounds__(256)
void scanB_k(int* __restrict__ bsum, int nb) {
    __shared__ int sh[256];
    int t = threadIdx.x;
    int v = (t < nb) ? bsum[t] : 0;
    sh[t] = v;
    __syncthreads();
#pragma unroll
    for (int off = 1; off < 256; off <<= 1) {
        int u = 0;
        if (t >= off) u = sh[t - off];
        __syncthreads();
        sh[t] += u;
        __syncthreads();
    }
    if (t < nb) bsum[t] = sh[t] - v;
}

__global__ __launch_bounds__(256)
void scanC_k(const int* __restrict__ cnt, const int* __restrict__ bsum,
             int* __restrict__ rowptr, int* __restrict__ cursor,
             float* __restrict__ dis, int n, int EN) {
    int i = blockIdx.x * 256 + threadIdx.x;
    if (i < n) {
        int r = rowptr[i] + bsum[blockIdx.x];
        rowptr[i] = r;
        cursor[i] = r;
        dis[i] = rsqrtf((float)cnt[i]);
    }
    if (i == 0) rowptr[n] = EN;
}

__global__ void scatter_k(const int* __restrict__ esrc, const int* __restrict__ edst,
                          int* __restrict__ cursor, int* __restrict__ colidx, int E, int EN) {
    int i = blockIdx.x * 256 + threadIdx.x;
    if (i >= EN) return;
    int s, d;
    if (i < E) { s = esrc[i]; d = edst[i]; }
    else       { s = i - E; d = s; }
    int pos = atomicAdd(&cursor[d], 1);
    colidx[pos] = s;
}

// ---------------- dense GEMM core: 4-row register blocked ----------------

#define FMA4R(A_, xv, w0, w1, w2, w3)                                  \
    A_.x += xv.x * w0.x + xv.y * w1.x + xv.z * w2.x + xv.w * w3.x;     \
    A_.y += xv.x * w0.y + xv.y * w1.y + xv.z * w2.y + xv.w * w3.y;     \
    A_.z += xv.x * w0.z + xv.y * w1.z + xv.z * w2.z + xv.w * w3.z;     \
    A_.w += xv.x * w0.w + xv.y * w1.w + xv.z * w2.w + xv.w * w3.w;

template <int K, int M>
__device__ __forceinline__ void gemm4(const float* __restrict__ Ws,
                                      const float* xa, const float* xb,
                                      const float* xc, const float* xd, int c,
                                      float4& A, float4& B, float4& C, float4& D) {
#pragma unroll 4
    for (int k = 0; k < K; k += 4) {
        float4 va = ld4(xa + k), vb = ld4(xb + k), vc = ld4(xc + k), vd = ld4(xd + k);
        const float* wp = Ws + k * M + c;
        float4 w0 = ld4(wp), w1 = ld4(wp + M), w2 = ld4(wp + 2 * M), w3 = ld4(wp + 3 * M);
        FMA4R(A, va, w0, w1, w2, w3)
        FMA4R(B, vb, w0, w1, w2, w3)
        FMA4R(C, vc, w0, w1, w2, w3)
        FMA4R(D, vd, w0, w1, w2, w3)
    }
}

__device__ __forceinline__ float4 f4bias(float4 v, float4 b) {
    return make_float4(v.x + b.x, v.y + b.y, v.z + b.z, v.w + b.w);
}
__device__ __forceinline__ float4 f4relu(float4 v) {
    return make_float4(fmaxf(v.x, 0.f), fmaxf(v.y, 0.f), fmaxf(v.z, 0.f), fmaxf(v.w, 0.f));
}
__device__ __forceinline__ float4 f4bn(float4 v, float4 g, float4 b) {
    return make_float4(v.x * g.x + b.x, v.y * g.y + b.y, v.z * g.z + b.z, v.w * g.w + b.w);
}

// input stage: 3 weight sets, same X (K=64, M=128)
__global__ __launch_bounds__(256)
void lin3_k(const float* __restrict__ X,
            const float* __restrict__ W0, const float* __restrict__ b0, float* __restrict__ Y0,
            const float* __restrict__ W1, const float* __restrict__ b1, float* __restrict__ Y1,
            const float* __restrict__ W2, const float* __restrict__ b2, float* __restrict__ Y2,
            int n, int gper) {
    constexpr int K = 64, M = 128, CG = 32, RPB = 8;
    int set = blockIdx.x / gper, blk = blockIdx.x % gper;
    const float* W = set == 0 ? W0 : (set == 1 ? W1 : W2);
    const float* bi = set == 0 ? b0 : (set == 1 ? b1 : b2);
    float* Y = set == 0 ? Y0 : (set == 1 ? Y1 : Y2);
    __shared__ float Ws[K * M];
    for (int i = threadIdx.x; i < K * M; i += 256) Ws[i] = W[i];
    __syncthreads();
    int cg = threadIdx.x % CG, r = threadIdx.x / CG, c = cg * 4;
    int ra = blk * (4 * RPB) + r, rb = ra + RPB, rc = ra + 2 * RPB, rd = ra + 3 * RPB;
    const float* xa = X + (size_t)(ra < n ? ra : 0) * K;
    const float* xb = X + (size_t)(rb < n ? rb : 0) * K;
    const float* xc = X + (size_t)(rc < n ? rc : 0) * K;
    const float* xd = X + (size_t)(rd < n ? rd : 0) * K;
    float4 A = f4z(), B = f4z(), C = f4z(), D = f4z();
    gemm4<K, M>(Ws, xa, xb, xc, xd, c, A, B, C, D);
    float4 bv = ld4(bi + c);
    A = f4bias(A, bv); B = f4bias(B, bv); C = f4bias(C, bv); D = f4bias(D, bv);
    if (ra < n) st4(Y + (size_t)ra * M + c, A);
    if (rb < n) st4(Y + (size_t)rb * M + c, B);
    if (rc < n) st4(Y + (size_t)rc * M + c, C);
    if (rd < n) st4(Y + (size_t)rd * M + c, D);
}

// per-layer pair: gcn half (Xg@Wg -> fp16 Yg), gat half (Xa@Wa -> fp16 Ya + attn dots)
__global__ __launch_bounds__(256)
void dual128_k(const float* __restrict__ Xg, const float* __restrict__ Wg, __half* __restrict__ Yg,
               const float* __restrict__ Xa, const float* __restrict__ Wa, __half* __restrict__ Ya,
               const float* __restrict__ asrc, const float* __restrict__ adst,
               float* __restrict__ avp, float* __restrict__ bvp, int hh,
               int n, int gper) {
    constexpr int K = 128, M = 128, CG = 32, RPB = 8;
    bool gat = blockIdx.x >= gper;
    int blk = gat ? blockIdx.x - gper : blockIdx.x;
    const float* X = gat ? Xa : Xg;
    const float* W = gat ? Wa : Wg;
    __half* Y = gat ? Ya : Yg;
    __shared__ float Ws[K * M];
    for (int i = threadIdx.x; i < K * M; i += 256) Ws[i] = W[i];
    __syncthreads();
    int cg = threadIdx.x % CG, r = threadIdx.x / CG, c = cg * 4;
    int ra = blk * (4 * RPB) + r, rb = ra + RPB, rc = ra + 2 * RPB, rd = ra + 3 * RPB;
    const float* xa = X + (size_t)(ra < n ? ra : 0) * K;
    const float* xb = X + (size_t)(rb < n ? rb : 0) * K;
    const float* xc = X + (size_t)(rc < n ? rc : 0) * K;
    const float* xd = X + (size_t)(rd < n ? rd : 0) * K;
    float4 A = f4z(), B = f4z(), C = f4z(), D = f4z();
    gemm4<K, M>(Ws, xa, xb, xc, xd, c, A, B, C, D);
    if (ra < n) sth4(Y + (size_t)ra * M + c, A);
    if (rb < n) sth4(Y + (size_t)rb * M + c, B);
    if (rc < n) sth4(Y + (size_t)rc * M + c, C);
    if (rd < n) sth4(Y + (size_t)rd * M + c, D);
    if (gat) {
        float4 as = ld4(asrc + c), ad = ld4(adst + c);
        float sa[4], sd[4];
        sa[0] = A.x * as.x + A.y * as.y + A.z * as.z + A.w * as.w;
        sa[1] = B.x * as.x + B.y * as.y + B.z * as.z + B.w * as.w;
        sa[2] = C.x * as.x + C.y * as.y + C.z * as.z + C.w * as.w;
        sa[3] = D.x * as.x + D.y * as.y + D.z * as.z + D.w * as.w;
        sd[0] = A.x * ad.x + A.y * ad.y + A.z * ad.z + A.w * ad.w;
        sd[1] = B.x * ad.x + B.y * ad.y + B.z * ad.z + B.w * ad.w;
        sd[2] = C.x * ad.x + C.y * ad.y + C.z * ad.z + C.w * ad.w;
        sd[3] = D.x * ad.x + D.y * ad.y + D.z * ad.z + D.w * ad.w;
        int gw = 32 / hh;   // lanes per head (8 or 32)
        for (int off = 1; off < gw; off <<= 1) {
#pragma unroll
            for (int j = 0; j < 4; ++j) {
                sa[j] += __shfl_xor(sa[j], off);
                sd[j] += __shfl_xor(sd[j], off);
            }
        }
        if ((cg & (gw - 1)) == 0) {
            int h = cg / gw;
            int rows[4] = {ra, rb, rc, rd};
#pragma unroll
            for (int j = 0; j < 4; ++j) {
                if (rows[j] < n) {
                    avp[rows[j] * hh + h] = sa[j];
                    bvp[rows[j] * hh + h] = sd[j];
                }
            }
        }
    }
}

// MLP-tail pair: two independent (X,W,b[,bn]) sets
template <int K, int M>
__global__ __launch_bounds__(256)
void tail2_k(const float* __restrict__ X0, const float* __restrict__ W0, const float* __restrict__ b0,
             const float* __restrict__ g0, const float* __restrict__ bb0, float* __restrict__ Y0,
             const float* __restrict__ X1, const float* __restrict__ W1, const float* __restrict__ b1,
             const float* __restrict__ g1, const float* __restrict__ bb1, float* __restrict__ Y1,
             int n, int gper, int do_relu) {
    constexpr int CG = M / 4, RPB = 256 / CG;
    bool s1 = blockIdx.x >= gper;
    int blk = s1 ? blockIdx.x - gper : blockIdx.x;
    const float* X = s1 ? X1 : X0;
    const float* W = s1 ? W1 : W0;
    const float* bi = s1 ? b1 : b0;
    const float* bg = s1 ? g1 : g0;
    const float* bb = s1 ? bb1 : bb0;
    float* Y = s1 ? Y1 : Y0;
    __shared__ float Ws[K * M];
    for (int i = threadIdx.x; i < K * M; i += 256) Ws[i] = W[i];
    __syncthreads();
    int cg = threadIdx.x % CG, r = threadIdx.x / CG, c = cg * 4;
    int ra = blk * (4 * RPB) + r, rb = ra + RPB, rc = ra + 2 * RPB, rd = ra + 3 * RPB;
    const float* xa = X + (size_t)(ra < n ? ra : 0) * K;
    const float* xb = X + (size_t)(rb < n ? rb : 0) * K;
    const float* xc = X + (size_t)(rc < n ? rc : 0) * K;
    const float* xd = X + (size_t)(rd < n ? rd : 0) * K;
    float4 A = f4z(), B = f4z(), C = f4z(), D = f4z();
    gemm4<K, M>(Ws, xa, xb, xc, xd, c, A, B, C, D);
    float4 bv = ld4(bi + c);
    A = f4bias(A, bv); B = f4bias(B, bv); C = f4bias(C, bv); D = f4bias(D, bv);
    if (do_relu) { A = f4relu(A); B = f4relu(B); C = f4relu(C); D = f4relu(D); }
    if (bg) {
        float4 g = ld4(bg + c);
        g = make_float4(g.x * RSQ_BN, g.y * RSQ_BN, g.z * RSQ_BN, g.w * RSQ_BN);
        float4 bbv = ld4(bb + c);
        A = f4bn(A, g, bbv); B = f4bn(B, g, bbv); C = f4bn(C, g, bbv); D = f4bn(D, g, bbv);
    }
    if (ra < n) st4(Y + (size_t)ra * M + c, A);
    if (rb < n) st4(Y + (size_t)rb * M + c, B);
    if (rc < n) st4(Y + (size_t)rc * M + c, C);
    if (rd < n) st4(Y + (size_t)rd * M + c, D);
}

// final: blend(0.6*XA+0.4*XB) @ fin -> relu -> bn -> @fin2 -> out[n,2]
__global__ __launch_bounds__(256)
void linF_k(const float* __restrict__ XA, const float* __restrict__ XB,
            const float* __restrict__ W, const float* __restrict__ bi,
            const float* __restrict__ bg, const float* __restrict__ bb,
            const float* __restrict__ w2, const float* __restrict__ b2,
            float* __restrict__ out, int n) {
    constexpr int K = 128, M = 64, CG = 16, RPB = 16;
    __shared__ float Ws[K * M];
    for (int i = threadIdx.x; i < K * M; i += 256) Ws[i] = W[i];
    __syncthreads();
    int cg = threadIdx.x % CG, r = threadIdx.x / CG, c = cg * 4;
    int ra = blockIdx.x * (4 * RPB) + r, rb = ra + RPB, rc = ra + 2 * RPB, rd = ra + 3 * RPB;
    const float* xa = XA + (size_t)(ra < n ? ra : 0) * K;
    const float* xb = XA + (size_t)(rb < n ? rb : 0) * K;
    const float* xc = XA + (size_t)(rc < n ? rc : 0) * K;
    const float* xd = XA + (size_t)(rd < n ? rd : 0) * K;
    const float* ya = XB + (size_t)(ra < n ? ra : 0) * K;
    const float* yb = XB + (size_t)(rb < n ? rb : 0) * K;
    const float* yc = XB + (size_t)(rc < n ? rc : 0) * K;
    const float* yd = XB + (size_t)(rd < n ? rd : 0) * K;
    float4 A = f4z(), B = f4z(), C = f4z(), D = f4z();
#pragma unroll 4
    for (int k = 0; k < K; k += 4) {
        float4 va = ld4(xa + k), vb = ld4(xb + k), vc = ld4(xc + k), vd = ld4(xd + k);
        float4 ua = ld4(ya + k), ub = ld4(yb + k), uc = ld4(yc + k), ud = ld4(yd + k);
        va = make_float4(0.6f * va.x + 0.4f * ua.x, 0.6f * va.y + 0.4f * ua.y,
                         0.6f * va.z + 0.4f * ua.z, 0.6f * va.w + 0.4f * ua.w);
        vb = make_float4(0.6f * vb.x + 0.4f * ub.x, 0.6f * vb.y + 0.4f * ub.y,
                         0.6f * vb.z + 0.4f * ub.z, 0.6f * vb.w + 0.4f * ub.w);
        vc = make_float4(0.6f * vc.x + 0.4f * uc.x, 0.6f * vc.y + 0.4f * uc.y,
                         0.6f * vc.z + 0.4f * uc.z, 0.6f * vc.w + 0.4f * uc.w);
        vd = make_float4(0.6f * vd.x + 0.4f * ud.x, 0.6f * vd.y + 0.4f * ud.y,
                         0.6f * vd.z + 0.4f * ud.z, 0.6f * vd.w + 0.4f * ud.w);
        const float* wp = Ws + k * M + c;
        float4 w0 = ld4(wp), w1 = ld4(wp + M), w2v = ld4(wp + 2 * M), w3 = ld4(wp + 3 * M);
        FMA4R(A, va, w0, w1, w2v, w3)
        FMA4R(B, vb, w0, w1, w2v, w3)
        FMA4R(C, vc, w0, w1, w2v, w3)
        FMA4R(D, vd, w0, w1, w2v, w3)
    }
    float4 bv = ld4(bi + c);
    A = f4relu(f4bias(A, bv)); B = f4relu(f4bias(B, bv));
    C = f4relu(f4bias(C, bv)); D = f4relu(f4bias(D, bv));
    float4 g = ld4(bg + c);
    g = make_float4(g.x * RSQ_BN, g.y * RSQ_BN, g.z * RSQ_BN, g.w * RSQ_BN);
    float4 bbv = ld4(bb + c);
    A = f4bn(A, g, bbv); B = f4bn(B, g, bbv); C = f4bn(C, g, bbv); D = f4bn(D, g, bbv);
    // classifier: per-row dot with w2[M,2]
    float w20 = w2[2 * c], w21 = w2[2 * c + 1];
    float w22 = w2[2 * c + 2], w23 = w2[2 * c + 3];
    float w24 = w2[2 * c + 4], w25 = w2[2 * c + 5];
    float w26 = w2[2 * c + 6], w27 = w2[2 * c + 7];
    float p0[4], p1[4];
    p0[0] = A.x * w20 + A.y * w22 + A.z * w24 + A.w * w26;
    p1[0] = A.x * w21 + A.y * w23 + A.z * w25 + A.w * w27;
    p0[1] = B.x * w20 + B.y * w22 + B.z * w24 + B.w * w26;
    p1[1] = B.x * w21 + B.y * w23 + B.z * w25 + B.w * w27;
    p0[2] = C.x * w20 + C.y * w22 + C.z * w24 + C.w * w26;
    p1[2] = C.x * w21 + C.y * w23 + C.z * w25 + C.w * w27;
    p0[3] = D.x * w20 + D.y * w22 + D.z * w24 + D.w * w26;
    p1[3] = D.x * w21 + D.y * w23 + D.z * w25 + D.w * w27;
    for (int off = 1; off < CG; off <<= 1) {
#pragma unroll
        for (int j = 0; j < 4; ++j) {
            p0[j] += __shfl_xor(p0[j], off);
            p1[j] += __shfl_xor(p1[j], off);
        }
    }
    if (cg == 0) {
        int rows[4] = {ra, rb, rc, rd};
#pragma unroll
        for (int j = 0; j < 4; ++j) {
            if (rows[j] < n) {
                out[rows[j] * 2] = p0[j] + b2[0];
                out[rows[j] * 2 + 1] = p1[j] + b2[1];
            }
        }
    }
}

// ---------------- merged sparse aggregation: gcn half + gat half ----------------
// 16 lanes/node, 8 cols (16B fp16) per lane.

__global__ __launch_bounds__(256)
void dual_gather_k(const int* __restrict__ rowptr, const int* __restrict__ colidx,
                   const float* __restrict__ dis,
                   const __half* __restrict__ Tg, const float* __restrict__ gbias,
                   const float* __restrict__ gbng, const float* __restrict__ gbnb,
                   const float* __restrict__ res, float* __restrict__ Yg,
                   const __half* __restrict__ Ta, const float* __restrict__ avp,
                   const float* __restrict__ bvp, const float* __restrict__ abias,
                   const float* __restrict__ abng, const float* __restrict__ abnb,
                   const float* __restrict__ fimp, float* __restrict__ Ya,
                   int n, int gper, int hh, int log2C) {
    bool gat = blockIdx.x >= gper;
    int blk = gat ? blockIdx.x - gper : blockIdx.x;
    int idx = blk * 256 + threadIdx.x;
    int i = idx >> 4;
    if (i >= n) return;
    int c = (idx & 15) * 8;
    int p0 = rowptr[i], p1 = rowptr[i + 1];
    float4 lo = f4z(), hi = f4z();

#define ACC8(qq, ww)                                                            \
    {                                                                           \
        float4 t0 = h4f(make_uint2(qq.x, qq.y)), t1 = h4f(make_uint2(qq.z, qq.w)); \
        lo.x += t0.x * ww; lo.y += t0.y * ww; lo.z += t0.z * ww; lo.w += t0.w * ww; \
        hi.x += t1.x * ww; hi.y += t1.y * ww; hi.z += t1.z * ww; hi.w += t1.w * ww; \
    }

    if (!gat) {
        int p = p0;
        for (; p + 4 <= p1; p += 4) {
            int s0 = colidx[p], s1 = colidx[p + 1], s2 = colidx[p + 2], s3 = colidx[p + 3];
            float w0 = dis[s0], w1 = dis[s1], w2 = dis[s2], w3 = dis[s3];
            uint4 q0 = *reinterpret_cast<const uint4*>(Tg + (size_t)s0 * 128 + c);
            uint4 q1 = *reinterpret_cast<const uint4*>(Tg + (size_t)s1 * 128 + c);
            uint4 q2 = *reinterpret_cast<const uint4*>(Tg + (size_t)s2 * 128 + c);
            uint4 q3 = *reinterpret_cast<const uint4*>(Tg + (size_t)s3 * 128 + c);
            ACC8(q0, w0) ACC8(q1, w1) ACC8(q2, w2) ACC8(q3, w3)
        }
        for (; p < p1; ++p) {
            int s0 = colidx[p];
            float w0 = dis[s0];
            uint4 q0 = *reinterpret_cast<const uint4*>(Tg + (size_t)s0 * 128 + c);
            ACC8(q0, w0)
        }
        float di = dis[i];
        float4 b0 = ld4(gbias + c), b1 = ld4(gbias + c + 4);
        lo = make_float4(lo.x * di + b0.x, lo.y * di + b0.y, lo.z * di + b0.z, lo.w * di + b0.w);
        hi = make_float4(hi.x * di + b1.x, hi.y * di + b1.y, hi.z * di + b1.z, hi.w * di + b1.w);
        float4 g0 = ld4(gbng + c), g1 = ld4(gbng + c + 4);
        g0 = make_float4(g0.x * RSQ_BN, g0.y * RSQ_BN, g0.z * RSQ_BN, g0.w * RSQ_BN);
        g1 = make_float4(g1.x * RSQ_BN, g1.y * RSQ_BN, g1.z * RSQ_BN, g1.w * RSQ_BN);
        float4 h0 = ld4(gbnb + c), h1 = ld4(gbnb + c + 4);
        lo = f4relu(f4bn(lo, g0, h0));
        hi = f4relu(f4bn(hi, g1, h1));
        if (res) {
            float4 r0 = ld4(res + (size_t)i * 128 + c), r1 = ld4(res + (size_t)i * 128 + c + 4);
            lo = f4bias(lo, r0); hi = f4bias(hi, r1);
        }
        st4(Yg + (size_t)i * 128 + c, lo);
        st4(Yg + (size_t)i * 128 + c + 4, hi);
    } else {
        int h = c >> log2C;
        float ad = bvp[i * hh + h];
        float m = -3.0e38f, s = 0.f;
        int p = p0;
        for (; p + 4 <= p1; p += 4) {
            int s0 = colidx[p], s1 = colidx[p + 1], s2 = colidx[p + 2], s3 = colidx[p + 3];
            float e0 = leaky02(avp[s0 * hh + h] + ad);
            float e1 = leaky02(avp[s1 * hh + h] + ad);
            float e2 = leaky02(avp[s2 * hh + h] + ad);
            float e3 = leaky02(avp[s3 * hh + h] + ad);
            uint4 q0 = *reinterpret_cast<const uint4*>(Ta + (size_t)s0 * 128 + c);
            uint4 q1 = *reinterpret_cast<const uint4*>(Ta + (size_t)s1 * 128 + c);
            uint4 q2 = *reinterpret_cast<const uint4*>(Ta + (size_t)s2 * 128 + c);
            uint4 q3 = *reinterpret_cast<const uint4*>(Ta + (size_t)s3 * 128 + c);
            float mn = fmaxf(m, fmaxf(fmaxf(e0, e1), fmaxf(e2, e3)));
            float scale = expf(m - mn);
            float w0 = expf(e0 - mn), w1 = expf(e1 - mn);
            float w2 = expf(e2 - mn), w3 = expf(e3 - mn);
            s = s * scale + ((w0 + w1) + (w2 + w3));
            lo = make_float4(lo.x * scale, lo.y * scale, lo.z * scale, lo.w * scale);
            hi = make_float4(hi.x * scale, hi.y * scale, hi.z * scale, hi.w * scale);
            ACC8(q0, w0) ACC8(q1, w1) ACC8(q2, w2) ACC8(q3, w3)
            m = mn;
        }
        for (; p < p1; ++p) {
            int s0 = colidx[p];
            float e0 = leaky02(avp[s0 * hh + h] + ad);
            float mn = fmaxf(m, e0);
            float scale = expf(m - mn);
            float w0 = expf(e0 - mn);
            s = s * scale + w0;
            lo = make_float4(lo.x * scale, lo.y * scale, lo.z * scale, lo.w * scale);
            hi = make_float4(hi.x * scale, hi.y * scale, hi.z * scale, hi.w * scale);
            uint4 q0 = *reinterpret_cast<const uint4*>(Ta + (size_t)s0 * 128 + c);
            ACC8(q0, w0)
            m = mn;
        }
        float si = 1.f / (s + 1e-16f);
        float4 b0 = ld4(abias + c), b1 = ld4(abias + c + 4);
        lo = make_float4(lo.x * si + b0.x, lo.y * si + b0.y, lo.z * si + b0.z, lo.w * si + b0.w);
        hi = make_float4(hi.x * si + b1.x, hi.y * si + b1.y, hi.z * si + b1.z, hi.w * si + b1.w);
        float4 g0 = ld4(abng + c), g1 = ld4(abng + c + 4);
        g0 = make_float4(g0.x * RSQ_BN, g0.y * RSQ_BN, g0.z * RSQ_BN, g0.w * RSQ_BN);
        g1 = make_float4(g1.x * RSQ_BN, g1.y * RSQ_BN, g1.z * RSQ_BN, g1.w * RSQ_BN);
        float4 h0 = ld4(abnb + c), h1 = ld4(abnb + c + 4);
        lo = f4bn(lo, g0, h0);
        hi = f4bn(hi, g1, h1);
        lo.x = lo.x > 0.f ? lo.x : expm1f(lo.x);
        lo.y = lo.y > 0.f ? lo.y : expm1f(lo.y);
        lo.z = lo.z > 0.f ? lo.z : expm1f(lo.z);
        lo.w = lo.w > 0.f ? lo.w : expm1f(lo.w);
        hi.x = hi.x > 0.f ? hi.x : expm1f(hi.x);
        hi.y = hi.y > 0.f ? hi.y : expm1f(hi.y);
        hi.z = hi.z > 0.f ? hi.z : expm1f(hi.z);
        hi.w = hi.w > 0.f ? hi.w : expm1f(hi.w);
        if (fimp) {
            float4 f0 = ld4(fimp + c), f1 = ld4(fimp + c + 4);
            lo = make_float4(lo.x * f0.x, lo.y * f0.y, lo.z * f0.z, lo.w * f0.w);
            hi = make_float4(hi.x * f1.x, hi.y * f1.y, hi.z * f1.z, hi.w * f1.w);
        }
        st4(Ya + (size_t)i * 128 + c, lo);
        st4(Ya + (size_t)i * 128 + c + 4, hi);
    }
#undef ACC8
}

// ---------------- host orchestration ----------------

static inline int cdiv(int a, int b) { return (a + b - 1) / b; }

extern "C" void kernel_launch(void* const* d_in, const int* in_sizes, int n_in,
                              void* d_out, int out_size, void* d_ws, size_t ws_size,
                              hipStream_t stream) {
    const float* x       = (const float*)d_in[0];
    const int*   ei      = (const int*)d_in[1];
    const float* gcn_in_w = (const float*)d_in[2];
    const float* gcn_in_b = (const float*)d_in[3];
    const float* gcn_res_w = (const float*)d_in[4];
    const float* gcn_res_b = (const float*)d_in[5];
    const float* gcn_w   = (const float*)d_in[6];
    const float* gcn_b   = (const float*)d_in[7];
    const float* gcn_bn_g = (const float*)d_in[8];
    const float* gcn_bn_b = (const float*)d_in[9];
    const float* gcn_c1w = (const float*)d_in[10];
    const float* gcn_c1b = (const float*)d_in[11];
    const float* gcn_c2w = (const float*)d_in[12];
    const float* gcn_c2b = (const float*)d_in[13];
    const float* gcn_c3w = (const float*)d_in[14];
    const float* gcn_c3b = (const float*)d_in[15];
    const float* gat_in_w = (const float*)d_in[16];
    const float* gat_in_b = (const float*)d_in[17];
    const float* gat_w   = (const float*)d_in[18];
    const float* gat_asrc = (const float*)d_in[19];
    const float* gat_adst = (const float*)d_in[20];
    const float* gat_b   = (const float*)d_in[21];
    const float* gat_bn_g = (const float*)d_in[22];
    const float* gat_bn_b = (const float*)d_in[23];
    const float* feat_imp = (const float*)d_in[24];
    const float* gat_c1w = (const float*)d_in[25];
    const float* gat_c1b = (const float*)d_in[26];
    const float* gat_cbn_g = (const float*)d_in[27];
    const float* gat_cbn_b = (const float*)d_in[28];
    const float* gat_c2w = (const float*)d_in[29];
    const float* gat_c2b = (const float*)d_in[30];
    const float* gat_c3w = (const float*)d_in[31];
    const float* gat_c3b = (const float*)d_in[32];
    const float* fin_w   = (const float*)d_in[33];
    const float* fin_b   = (const float*)d_in[34];
    const float* fin_bn_g = (const float*)d_in[35];
    const float* fin_bn_b = (const float*)d_in[36];
    const float* fin2_w  = (const float*)d_in[37];
    const float* fin2_b  = (const float*)d_in[38];

    const int N = in_sizes[0] / 64;
    const int E = in_sizes[1] / 2;
    const int EN = E + N;
    const int* esrc = ei;
    const int* edst = ei + E;

    // workspace carve (256B aligned)
    char* wp = (char*)d_ws;
    auto alloc = [&](size_t bytes) -> void* {
        void* p = (void*)wp;
        wp += (bytes + 255) & ~(size_t)255;
        return p;
    };
    int* cnt    = (int*)alloc((size_t)N * 4);
    int* rowptr = (int*)alloc((size_t)(N + 1) * 4);
    int* cursor = (int*)alloc((size_t)N * 4);
    int* bsum   = (int*)alloc((size_t)256 * 4);
    int* colidx = (int*)alloc((size_t)EN * 4);
    float* dis  = (float*)alloc((size_t)N * 4);
    float* A    = (float*)alloc((size_t)N * 128 * 4);   // gcn ping / GOUT reuse
    float* B    = (float*)alloc((size_t)N * 128 * 4);   // gcn pong
    float* G    = (float*)alloc((size_t)N * 128 * 4);   // gat ping / AOUT reuse
    float* H    = (float*)alloc((size_t)N * 128 * 4);   // gat pong
    float* R    = (float*)alloc((size_t)N * 128 * 4);   // gcn residual
    __half* Th1 = (__half*)alloc((size_t)N * 128 * 2);  // aliased as h1g after layers
    __half* Th2 = (__half*)alloc((size_t)N * 128 * 2);  // aliased as h1a after layers
    float* h2g  = (float*)alloc((size_t)N * 32 * 4);
    float* h2a  = (float*)alloc((size_t)N * 32 * 4);
    float* avv  = (float*)alloc((size_t)N * 4 * 4);
    float* bvv  = (float*)alloc((size_t)N * 4 * 4);
    float* h1g = (float*)Th1;   // N*64*4 == N*128*2 bytes
    float* h1a = (float*)Th2;

    // ---- CSR build ----
    const int nScanB = cdiv(N, 256);
    zero_i32_k<<<cdiv(N, 256), 256, 0, stream>>>(cnt, N);
    hist_k<<<cdiv(EN, 256), 256, 0, stream>>>(edst, cnt, E, EN);
    scanA_k<<<nScanB, 256, 0, stream>>>(cnt, rowptr, bsum, N);
    scanB_k<<<1, 256, 0, stream>>>(bsum, nScanB);
    scanC_k<<<nScanB, 256, 0, stream>>>(cnt, bsum, rowptr, cursor, dis, N, EN);
    scatter_k<<<cdiv(EN, 256), 256, 0, stream>>>(esrc, edst, cursor, colidx, E, EN);

    const int g32r  = cdiv(N, 32);    // M=128, 4-row blocks
    const int g64r  = cdiv(N, 64);    // M=64
    const int g128r = cdiv(N, 128);   // M=32
    const int gG    = cdiv(N, 16);    // gather: 16 nodes/block

    // ---- input stage: gcn_in -> A, gcn_res -> R, gat_in -> G ----
    lin3_k<<<3 * g32r, 256, 0, stream>>>(x, gcn_in_w, gcn_in_b, A,
                                         gcn_res_w, gcn_res_b, R,
                                         gat_in_w, gat_in_b, G, N, g32r);

    // ---- 3 layers, both branches in lockstep ----
    const int heads_arr[3] = {4, 4, 1};
    float* gcur = A; float* gnxt = B;
    float* acur = G; float* anxt = H;
    for (int i = 0; i < 3; ++i) {
        int hh = heads_arr[i];
        int log2C = (hh == 4) ? 5 : 7;
        dual128_k<<<2 * g32r, 256, 0, stream>>>(gcur, gcn_w + (size_t)i * 16384, Th1,
                                                acur, gat_w + (size_t)i * 16384, Th2,
                                                gat_asrc + i * 128, gat_adst + i * 128,
                                                avv, bvv, hh, N, g32r);
        dual_gather_k<<<2 * gG, 256, 0, stream>>>(rowptr, colidx, dis,
                                                  Th1, gcn_b + i * 128, gcn_bn_g + i * 128,
                                                  gcn_bn_b + i * 128, (i == 1) ? R : nullptr, gnxt,
                                                  Th2, avv, bvv, gat_b + i * 128,
                                                  gat_bn_g + i * 128, gat_bn_b + i * 128,
                                                  (i == 2) ? feat_imp : nullptr, anxt,
                                                  N, gG, hh, log2C);
        float* t = gcur; gcur = gnxt; gnxt = t;
        t = acur; acur = anxt; anxt = t;
    }
    // gcur = gcn final xp (B), acur = gat final xg (H)

    // ---- MLP tails (pairs) ----  (h1g/h1a alias Th1/Th2 — Th no longer needed)
    tail2_k<128, 64><<<2 * g64r, 256, 0, stream>>>(
        gcur, gcn_c1w, gcn_c1b, nullptr, nullptr, h1g,
        acur, gat_c1w, gat_c1b, gat_cbn_g, gat_cbn_b, h1a, N, g64r, 1);
    tail2_k<64, 32><<<2 * g128r, 256, 0, stream>>>(
        h1g, gcn_c2w, gcn_c2b, nullptr, nullptr, h2g,
        h1a, gat_c2w, gat_c2b, nullptr, nullptr, h2a, N, g128r, 1);
    tail2_k<32, 128><<<2 * g32r, 256, 0, stream>>>(
        h2g, gcn_c3w, gcn_c3b, nullptr, nullptr, A,
        h2a, gat_c3w, gat_c3b, nullptr, nullptr, G, N, g32r, 0);

    // ---- fusion tail: blend + fin linear + bn + classifier ----
    linF_k<<<g64r, 256, 0, stream>>>(A, G, fin_w, fin_b, fin_bn_g, fin_bn_b,
                                     fin2_w, fin2_b, (float*)d_out, N);
}